// Round 3
// baseline (2550.874 us; speedup 1.0000x reference)
//
#include <hip/hip_runtime.h>
#include <hip/hip_bf16.h>
#include <math.h>

#define NN 50000      // nodes
#define NE 800000     // edges (without self loops)
#define NEP 850000    // edges + self loops
#define NG 64         // graphs

// order-preserving float -> uint key (monotonic for all finite floats, incl +-0)
__device__ __forceinline__ unsigned fkey(float f) {
    unsigned u = __float_as_uint(f);
    return (u & 0x80000000u) ? ~u : (u | 0x80000000u);
}
__device__ __forceinline__ float fkey_inv(unsigned k) {
    return (k & 0x80000000u) ? __uint_as_float(k ^ 0x80000000u) : __uint_as_float(~k);
}

// ---------------- GEMM: H[n,dout] = X[n,din] @ W[din,dout] ----------------
// block (64,4); each thread does 4 rows => 16 rows/block. NN % 16 == 0.
__global__ void k_gemm(const float* __restrict__ X, const float* __restrict__ W,
                       float* __restrict__ H, int nrows, int din, int dout) {
    int o  = blockIdx.x * 64 + threadIdx.x;
    int n0 = (blockIdx.y * blockDim.y + threadIdx.y) * 4;
    if (n0 + 3 >= nrows) {
        for (int r = 0; r < 4; r++) {
            int n = n0 + r;
            if (n >= nrows) return;
            float acc = 0.f;
            for (int k = 0; k < din; k++) acc += X[(size_t)n * din + k] * W[(size_t)k * dout + o];
            H[(size_t)n * dout + o] = acc;
        }
        return;
    }
    const float* x0 = X + (size_t)n0 * din;
    float a0 = 0.f, a1 = 0.f, a2 = 0.f, a3 = 0.f;
    for (int k = 0; k < din; k++) {
        float w = W[(size_t)k * dout + o];
        a0 += x0[k] * w;
        a1 += x0[din + k] * w;
        a2 += x0[2 * din + k] * w;
        a3 += x0[3 * din + k] * w;
    }
    float* h0 = H + (size_t)n0 * dout + o;
    h0[0] = a0; h0[dout] = a1; h0[2 * dout] = a2; h0[3 * dout] = a3;
}

// ---------------- per-node projections s = h . a_src, t = h . a_dst ----------------
__global__ void k_proj(const float* __restrict__ H, const float* __restrict__ asv,
                       const float* __restrict__ adv, float* __restrict__ s,
                       float* __restrict__ t, int dout) {
    int gid = blockIdx.x * blockDim.x + threadIdx.x;
    int node = gid >> 6, lane = gid & 63;
    if (node >= NN) return;
    const float* h = H + (size_t)node * dout;
    float a = 0.f, b = 0.f;
    for (int o = lane; o < dout; o += 64) {
        float hv = h[o];
        a += hv * asv[o];
        b += hv * adv[o];
    }
    for (int off = 32; off; off >>= 1) {
        a += __shfl_xor(a, off);
        b += __shfl_xor(b, off);
    }
    if (lane == 0) { s[node] = a; t[node] = b; }
}

// ---------------- per-node init ----------------
__global__ void k_init_denom(float* __restrict__ denom) {
    int i = blockIdx.x * blockDim.x + threadIdx.x;
    if (i < NN) denom[i] = 0.f;
}

// OUT[n, o] = bias[o]   (bias-initialized accumulator)
__global__ void k_init_out(float* __restrict__ OUT, const float* __restrict__ bias, int dout) {
    int i = blockIdx.x * blockDim.x + threadIdx.x;
    if (i < NN * dout) OUT[i] = bias[i & (dout - 1)];
}

// ---------------- edge pass 1: e = leakyrelu(s[src]+t[dst]); ex = exp(e); denom += ex
// (softmax is shift-invariant; |e| is O(1) here so no max-subtraction needed)
__global__ void k_edge_e(const int* __restrict__ src, const int* __restrict__ dst,
                         const float* __restrict__ s, const float* __restrict__ t,
                         float* __restrict__ ebuf, float* __restrict__ denom) {
    int i = blockIdx.x * blockDim.x + threadIdx.x;
    if (i >= NEP) return;
    int sv = (i < NE) ? src[i] : (i - NE);
    int dv = (i < NE) ? dst[i] : (i - NE);
    float e = s[sv] + t[dv];
    e = (e > 0.f) ? e : 0.2f * e;
    float ex = expf(e);
    ebuf[i] = ex;
    atomicAdd(&denom[dv], ex);
}

// ---------------- edge pass 2: OUT[dst] += alpha * H[src], wave per edge ----------------
__global__ void k_edge3(const int* __restrict__ src, const int* __restrict__ dst,
                        const float* __restrict__ ebuf, const float* __restrict__ denom,
                        const float* __restrict__ H, float* __restrict__ OUT, int dout) {
    int gid = blockIdx.x * blockDim.x + threadIdx.x;
    int e = gid >> 6, lane = gid & 63;
    if (e >= NEP) return;
    int sv = (e < NE) ? src[e] : (e - NE);
    int dv = (e < NE) ? dst[e] : (e - NE);
    float alpha = ebuf[e] / denom[dv];
    const float* hrow = H + (size_t)sv * dout;
    float* orow = OUT + (size_t)dv * dout;
    for (int o = lane; o < dout; o += 64)
        atomicAdd(&orow[o], alpha * hrow[o]);
}

// ---------------- pooling ----------------
__global__ void k_pool_init(unsigned* __restrict__ x1k, float* __restrict__ x2, float* __restrict__ cnt) {
    int i = blockIdx.x * blockDim.x + threadIdx.x;
    if (i < NG * 256) { x1k[i] = 0u; x2[i] = 0.f; }   // key 0 < fkey(any finite)
    if (i < NG) cnt[i] = 0.f;
}

__global__ void k_pool(const float* __restrict__ H, const int* __restrict__ batch,
                       unsigned* __restrict__ x1k, float* __restrict__ x2, float* __restrict__ cnt) {
    int gid = blockIdx.x * blockDim.x + threadIdx.x;
    int node = gid >> 6, lane = gid & 63;
    if (node >= NN) return;
    int g = batch[node];
    const float* h = H + (size_t)node * 256;
    unsigned* m1 = x1k + (size_t)g * 256;
    float* s2 = x2 + (size_t)g * 256;
    for (int o = lane; o < 256; o += 64) {
        float hv = h[o];
        atomicMax(&m1[o], fkey(hv));
        atomicAdd(&s2[o], hv);
    }
    if (lane == 0) atomicAdd(&cnt[g], 1.f);
}

// z512 = concat(max, sum); x3 = sum / max(cnt,1)
__global__ void k_buildz(const unsigned* __restrict__ x1k, const float* __restrict__ x2,
                         const float* __restrict__ cnt, float* __restrict__ z512,
                         float* __restrict__ x3) {
    int i = blockIdx.x * blockDim.x + threadIdx.x;
    if (i >= NG * 256) return;
    int g = i >> 8, o = i & 255;
    z512[(size_t)g * 512 + o] = fkey_inv(x1k[i]);
    z512[(size_t)g * 512 + 256 + o] = x2[i];
    x3[i] = x2[i] / fmaxf(cnt[g], 1.f);
}

// ---------------- dense: out[g,dout] = act(in[g,din] @ W + b). block=dout, grid=NG ----------------
// act: 0 none, 1 relu, 2 sigmoid
__global__ void k_dense(const float* __restrict__ in, const float* __restrict__ W,
                        const float* __restrict__ b, float* __restrict__ out,
                        int din, int dout, int act) {
    __shared__ float row[512];
    int g = blockIdx.x, o = threadIdx.x;
    for (int k = o; k < din; k += blockDim.x) row[k] = in[(size_t)g * din + k];
    __syncthreads();
    float acc = b[o];
    for (int k = 0; k < din; k++) acc += row[k] * W[(size_t)k * dout + o];
    if (act == 1) acc = fmaxf(acc, 0.f);
    else if (act == 2) acc = 1.f / (1.f + expf(-acc));
    out[(size_t)g * dout + o] = acc;
}

__global__ void k_mul(float* __restrict__ a, const float* __restrict__ b, int n) {
    int i = blockIdx.x * blockDim.x + threadIdx.x;
    if (i < n) a[i] *= b[i];
}

// =====================================================================
extern "C" void kernel_launch(void* const* d_in, const int* in_sizes, int n_in,
                              void* d_out, int out_size, void* d_ws, size_t ws_size,
                              hipStream_t stream) {
    const float* x_in  = (const float*)d_in[0];
    const int*   ei    = (const int*)d_in[1];
    const int*   batch = (const int*)d_in[2];
    const int* src = ei;
    const int* dst = ei + NE;

    const float* Wl[3]   = { (const float*)d_in[3], (const float*)d_in[7],  (const float*)d_in[11] };
    const float* asl[3]  = { (const float*)d_in[4], (const float*)d_in[8],  (const float*)d_in[12] };
    const float* adl[3]  = { (const float*)d_in[5], (const float*)d_in[9],  (const float*)d_in[13] };
    const float* bl[3]   = { (const float*)d_in[6], (const float*)d_in[10], (const float*)d_in[14] };
    const int din[3]  = {128, 64, 128};
    const int dout[3] = {64, 128, 256};

    const float* d1w = (const float*)d_in[15]; const float* d1b = (const float*)d_in[16];
    const float* d2w = (const float*)d_in[17]; const float* d2b = (const float*)d_in[18];
    const float* d3w = (const float*)d_in[19]; const float* d3b = (const float*)d_in[20];
    const float* mw  = (const float*)d_in[21]; const float* mb  = (const float*)d_in[22];
    const float* d4w = (const float*)d_in[23]; const float* d4b = (const float*)d_in[24];
    const float* d5w = (const float*)d_in[25]; const float* d5b = (const float*)d_in[26];
    const float* d6w = (const float*)d_in[27]; const float* d6b = (const float*)d_in[28];
    const float* d7w = (const float*)d_in[29]; const float* d7b = (const float*)d_in[30];

    // -------- workspace carve (floats) --------
    float* ws = (float*)d_ws;
    size_t off = 0;
    float* Xbuf  = ws + off; off += (size_t)NN * 256;   // layer output accumulator / next input
    float* Hbuf  = ws + off; off += (size_t)NN * 256;   // transformed features
    float* sbuf  = ws + off; off += NN;
    float* tbuf  = ws + off; off += NN;
    float* dnbuf = ws + off; off += NN;
    float* ebuf  = ws + off; off += NEP;
    unsigned* x1k = (unsigned*)(ws + off); off += NG * 256;
    float* x2    = ws + off; off += NG * 256;
    float* cnt   = ws + off; off += NG;
    float* z512  = ws + off; off += NG * 512;
    float* x3    = ws + off; off += NG * 256;
    float* tA    = ws + off; off += NG * 256;
    float* tB    = ws + off; off += NG * 256;
    float* gate  = ws + off; off += NG * 64;

    // -------- three GAT layers --------
    for (int l = 0; l < 3; l++) {
        int di = din[l], doo = dout[l];
        const float* X = (l == 0) ? x_in : Xbuf;   // layer 0 reads the f32 input directly
        // H = X @ W
        dim3 gblk(64, 4);
        dim3 ggrd(doo / 64, NN / 16);
        k_gemm<<<ggrd, gblk, 0, stream>>>(X, Wl[l], Hbuf, NN, di, doo);
        // s, t projections
        k_proj<<<(NN * 64 + 255) / 256, 256, 0, stream>>>(Hbuf, asl[l], adl[l], sbuf, tbuf, doo);
        // init denom, OUT (Xbuf becomes the accumulator, init with bias)
        k_init_denom<<<(NN + 255) / 256, 256, 0, stream>>>(dnbuf);
        k_init_out<<<(NN * doo + 255) / 256, 256, 0, stream>>>(Xbuf, bl[l], doo);
        // edge passes
        k_edge_e<<<(NEP + 255) / 256, 256, 0, stream>>>(src, dst, sbuf, tbuf, ebuf, dnbuf);
        k_edge3<<<((size_t)NEP * 64 + 255) / 256, 256, 0, stream>>>(src, dst, ebuf, dnbuf, Hbuf, Xbuf, doo);
    }

    // -------- pooling --------
    k_pool_init<<<(NG * 256 + 255) / 256, 256, 0, stream>>>(x1k, x2, cnt);
    k_pool<<<(NN * 64 + 255) / 256, 256, 0, stream>>>(Xbuf, batch, x1k, x2, cnt);
    k_buildz<<<(NG * 256 + 255) / 256, 256, 0, stream>>>(x1k, x2, cnt, z512, x3);

    // -------- dense tail --------
    k_dense<<<NG, 256, 0, stream>>>(z512, d1w, d1b, tA, 512, 256, 1);   // d1 relu -> [64,256]
    k_dense<<<NG, 128, 0, stream>>>(tA,   d2w, d2b, tB, 256, 128, 1);   // d2 relu -> [64,128]
    k_dense<<<NG,  64, 0, stream>>>(tB,   d3w, d3b, tA, 128,  64, 1);   // d3 relu -> [64,64]
    k_dense<<<NG,  64, 0, stream>>>(x3,   mw,  mb,  gate, 256, 64, 2);  // sigmoid gate [64,64]
    k_mul<<<(NG * 64 + 255) / 256, 256, 0, stream>>>(tA, gate, NG * 64);
    k_dense<<<NG,  64, 0, stream>>>(tA,   d4w, d4b, tB,  64,  64, 1);   // d4 relu
    k_dense<<<NG, 128, 0, stream>>>(tB,   d5w, d5b, tA,  64, 128, 1);   // d5 relu
    k_dense<<<NG, 256, 0, stream>>>(tA,   d6w, d6b, tB, 128, 256, 1);   // d6 relu
    k_dense<<<NG, 128, 0, stream>>>(tB,   d7w, d7b, (float*)d_out, 256, 128, 0); // d7 -> [64,128] f32 out
}

// Round 4
// 1165.334 us; speedup vs baseline: 2.1890x; 2.1890x over previous
//
#include <hip/hip_runtime.h>
#include <hip/hip_bf16.h>
#include <math.h>

#define NN 50000      // nodes
#define NE 800000     // edges (without self loops)
#define NEP 850000    // edges + self loops
#define NG 64         // graphs
#define SCAN_B 256

// order-preserving float -> uint key (monotonic for all finite floats, incl +-0)
__device__ __forceinline__ unsigned fkey(float f) {
    unsigned u = __float_as_uint(f);
    return (u & 0x80000000u) ? ~u : (u | 0x80000000u);
}
__device__ __forceinline__ float fkey_inv(unsigned k) {
    return (k & 0x80000000u) ? __uint_as_float(k ^ 0x80000000u) : __uint_as_float(~k);
}

// ================= CSR build =================
__global__ void k_zero_int(int* __restrict__ p, int n) {
    int i = blockIdx.x * blockDim.x + threadIdx.x;
    if (i < n) p[i] = 0;
}

__global__ void k_hist(const int* __restrict__ dst, int* __restrict__ deg) {
    int i = blockIdx.x * blockDim.x + threadIdx.x;
    if (i >= NEP) return;
    int dv = (i < NE) ? dst[i] : (i - NE);
    atomicAdd(&deg[dv], 1);
}

// block-level exclusive scan (Hillis-Steele in LDS)
__global__ void k_scan1(const int* __restrict__ deg, int* __restrict__ excl,
                        int* __restrict__ partials, int n) {
    __shared__ int sh[SCAN_B];
    int i = blockIdx.x * SCAN_B + threadIdx.x;
    int v = (i < n) ? deg[i] : 0;
    sh[threadIdx.x] = v;
    __syncthreads();
    for (int off = 1; off < SCAN_B; off <<= 1) {
        int t = (threadIdx.x >= off) ? sh[threadIdx.x - off] : 0;
        __syncthreads();
        sh[threadIdx.x] += t;
        __syncthreads();
    }
    if (i < n) excl[i] = sh[threadIdx.x] - v;
    if (threadIdx.x == SCAN_B - 1) partials[blockIdx.x] = sh[threadIdx.x];
}

__global__ void k_scan2(int* __restrict__ partials, int nb) {  // single block, nb <= 256
    __shared__ int sh[SCAN_B];
    int v = (threadIdx.x < nb) ? partials[threadIdx.x] : 0;
    sh[threadIdx.x] = v;
    __syncthreads();
    for (int off = 1; off < SCAN_B; off <<= 1) {
        int t = (threadIdx.x >= off) ? sh[threadIdx.x - off] : 0;
        __syncthreads();
        sh[threadIdx.x] += t;
        __syncthreads();
    }
    if (threadIdx.x < nb) partials[threadIdx.x] = sh[threadIdx.x] - v;
}

__global__ void k_scan3(const int* __restrict__ excl, const int* __restrict__ partials,
                        int* __restrict__ rowptr, int* __restrict__ cursor, int n) {
    int i = blockIdx.x * SCAN_B + threadIdx.x;
    if (i < n) {
        int r = excl[i] + partials[blockIdx.x];
        rowptr[i] = r;
        cursor[i] = r;
    }
    if (i == 0) rowptr[n] = NEP;
}

__global__ void k_scatter(const int* __restrict__ src, const int* __restrict__ dst,
                          int* __restrict__ cursor, int* __restrict__ srcsort) {
    int i = blockIdx.x * blockDim.x + threadIdx.x;
    if (i >= NEP) return;
    int sv = (i < NE) ? src[i] : (i - NE);
    int dv = (i < NE) ? dst[i] : (i - NE);
    int pos = atomicAdd(&cursor[dv], 1);
    srcsort[pos] = sv;
}

// ================= GEMM: H[NN,dout] = X[NN,din] @ W[din,dout] =================
// block (64,4): 16 rows/block, OPT outputs/thread (dout = 64*OPT), X tile in LDS.
template<int OPT>
__global__ void k_gemm_t(const float* __restrict__ X, const float* __restrict__ W,
                         float* __restrict__ H, int din) {
    const int dout = 64 * OPT;
    __shared__ float xs[16 * 128];
    int tx = threadIdx.x, ty = threadIdx.y;
    int tid = ty * 64 + tx;
    int n0 = blockIdx.y * 16;
    for (int idx = tid; idx < 16 * din; idx += 256)
        xs[idx] = X[(size_t)n0 * din + idx];   // 16 consecutive rows are contiguous
    __syncthreads();
    int rbase = ty * 4;
    float acc[4][OPT];
#pragma unroll
    for (int r = 0; r < 4; r++)
#pragma unroll
        for (int o = 0; o < OPT; o++) acc[r][o] = 0.f;
    for (int k = 0; k < din; k++) {
        float w[OPT];
        if constexpr (OPT == 4) {
            float4 t4 = *(const float4*)(W + (size_t)k * dout + tx * 4);
            w[0] = t4.x; w[1] = t4.y; w[2] = t4.z; w[3] = t4.w;
        } else if constexpr (OPT == 2) {
            float2 t2 = *(const float2*)(W + (size_t)k * dout + tx * 2);
            w[0] = t2.x; w[1] = t2.y;
        } else {
            w[0] = W[(size_t)k * dout + tx];
        }
#pragma unroll
        for (int r = 0; r < 4; r++) {
            float xv = xs[(rbase + r) * din + k];
#pragma unroll
            for (int o = 0; o < OPT; o++) acc[r][o] += xv * w[o];
        }
    }
#pragma unroll
    for (int r = 0; r < 4; r++) {
        float* out = H + (size_t)(n0 + rbase + r) * dout + tx * OPT;
        if constexpr (OPT == 4) *(float4*)out = make_float4(acc[r][0], acc[r][1], acc[r][2], acc[r][3]);
        else if constexpr (OPT == 2) *(float2*)out = make_float2(acc[r][0], acc[r][1]);
        else out[0] = acc[r][0];
    }
}

// ================= per-node projections s = h.a_src, t = h.a_dst =================
__global__ void k_proj(const float* __restrict__ H, const float* __restrict__ asv,
                       const float* __restrict__ adv, float* __restrict__ s,
                       float* __restrict__ t, int dout) {
    int gid = blockIdx.x * blockDim.x + threadIdx.x;
    int node = gid >> 6, lane = gid & 63;
    if (node >= NN) return;
    const float* h = H + (size_t)node * dout;
    float a = 0.f, b = 0.f;
    for (int o = lane; o < dout; o += 64) {
        float hv = h[o];
        a += hv * asv[o];
        b += hv * adv[o];
    }
#pragma unroll
    for (int off = 32; off; off >>= 1) {
        a += __shfl_xor(a, off);
        b += __shfl_xor(b, off);
    }
    if (lane == 0) { s[node] = a; t[node] = b; }
}

// ================= fused softmax + aggregation: wave per dst node =================
// OUT[n] = bias + sum_j alpha_j * H[src_j];  alpha = softmax over incoming edges.
// Softmax computed shift-free (|e| is O(1), exp cannot overflow).
template<int DOUT>
__global__ void k_agg(const int* __restrict__ rowptr, const int* __restrict__ srcsort,
                      const float* __restrict__ s, const float* __restrict__ t,
                      const float* __restrict__ H, const float* __restrict__ bias,
                      float* __restrict__ OUT) {
    constexpr int R = DOUT / 64;
    int node = blockIdx.x * 4 + (threadIdx.x >> 6);
    int lane = threadIdx.x & 63;
    if (node >= NN) return;
    int beg = rowptr[node], end = rowptr[node + 1];
    float tn = t[node];
    // phase 1: denominator (lanes parallel over edges)
    float dsum = 0.f;
    for (int j = beg + lane; j < end; j += 64) {
        float e = s[srcsort[j]] + tn;
        e = (e > 0.f) ? e : 0.2f * e;
        dsum += expf(e);
    }
#pragma unroll
    for (int off = 32; off; off >>= 1) dsum += __shfl_xor(dsum, off);
    float inv = 1.f / dsum;   // >0 guaranteed: self-loop edge always present
    // phase 2: weighted gather (lanes parallel over features, serial over edges)
    float acc[R];
    if constexpr (R == 4) {
        float4 b4 = ((const float4*)bias)[lane];
        acc[0] = b4.x; acc[1] = b4.y; acc[2] = b4.z; acc[3] = b4.w;
    } else if constexpr (R == 2) {
        float2 b2 = ((const float2*)bias)[lane];
        acc[0] = b2.x; acc[1] = b2.y;
    } else {
        acc[0] = bias[lane];
    }
    for (int j = beg; j < end; j++) {
        int sv = srcsort[j];                       // wave-uniform
        float e = s[sv] + tn;
        e = (e > 0.f) ? e : 0.2f * e;
        float alpha = expf(e) * inv;
        const float* hrow = H + (size_t)sv * DOUT;
        if constexpr (R == 4) {
            float4 v = ((const float4*)hrow)[lane];
            acc[0] += alpha * v.x; acc[1] += alpha * v.y;
            acc[2] += alpha * v.z; acc[3] += alpha * v.w;
        } else if constexpr (R == 2) {
            float2 v = ((const float2*)hrow)[lane];
            acc[0] += alpha * v.x; acc[1] += alpha * v.y;
        } else {
            acc[0] += alpha * hrow[lane];
        }
    }
    float* orow = OUT + (size_t)node * DOUT;
    if constexpr (R == 4) ((float4*)orow)[lane] = make_float4(acc[0], acc[1], acc[2], acc[3]);
    else if constexpr (R == 2) ((float2*)orow)[lane] = make_float2(acc[0], acc[1]);
    else orow[lane] = acc[0];
}

// ================= pooling =================
__global__ void k_pool_init(unsigned* __restrict__ x1k, float* __restrict__ x2, float* __restrict__ cnt) {
    int i = blockIdx.x * blockDim.x + threadIdx.x;
    if (i < NG * 256) { x1k[i] = 0u; x2[i] = 0.f; }   // key 0 < fkey(any finite)
    if (i < NG) cnt[i] = 0.f;
}

__global__ void k_pool(const float* __restrict__ H, const int* __restrict__ batch,
                       unsigned* __restrict__ x1k, float* __restrict__ x2, float* __restrict__ cnt) {
    int gid = blockIdx.x * blockDim.x + threadIdx.x;
    int node = gid >> 6, lane = gid & 63;
    if (node >= NN) return;
    int g = batch[node];
    const float* h = H + (size_t)node * 256;
    unsigned* m1 = x1k + (size_t)g * 256;
    float* s2 = x2 + (size_t)g * 256;
    for (int o = lane; o < 256; o += 64) {
        float hv = h[o];
        atomicMax(&m1[o], fkey(hv));
        atomicAdd(&s2[o], hv);
    }
    if (lane == 0) atomicAdd(&cnt[g], 1.f);
}

__global__ void k_buildz(const unsigned* __restrict__ x1k, const float* __restrict__ x2,
                         const float* __restrict__ cnt, float* __restrict__ z512,
                         float* __restrict__ x3) {
    int i = blockIdx.x * blockDim.x + threadIdx.x;
    if (i >= NG * 256) return;
    int g = i >> 8, o = i & 255;
    z512[(size_t)g * 512 + o] = fkey_inv(x1k[i]);
    z512[(size_t)g * 512 + 256 + o] = x2[i];
    x3[i] = x2[i] / fmaxf(cnt[g], 1.f);
}

// ================= dense tail =================
__global__ void k_dense(const float* __restrict__ in, const float* __restrict__ W,
                        const float* __restrict__ b, float* __restrict__ out,
                        int din, int dout, int act) {
    __shared__ float row[512];
    int g = blockIdx.x, o = threadIdx.x;
    for (int k = o; k < din; k += blockDim.x) row[k] = in[(size_t)g * din + k];
    __syncthreads();
    float acc = b[o];
    for (int k = 0; k < din; k++) acc += row[k] * W[(size_t)k * dout + o];
    if (act == 1) acc = fmaxf(acc, 0.f);
    else if (act == 2) acc = 1.f / (1.f + expf(-acc));
    out[(size_t)g * dout + o] = acc;
}

__global__ void k_mul(float* __restrict__ a, const float* __restrict__ b, int n) {
    int i = blockIdx.x * blockDim.x + threadIdx.x;
    if (i < n) a[i] *= b[i];
}

// =====================================================================
extern "C" void kernel_launch(void* const* d_in, const int* in_sizes, int n_in,
                              void* d_out, int out_size, void* d_ws, size_t ws_size,
                              hipStream_t stream) {
    const float* x_in  = (const float*)d_in[0];
    const int*   ei    = (const int*)d_in[1];
    const int*   batch = (const int*)d_in[2];
    const int* src = ei;
    const int* dst = ei + NE;

    const float* Wl[3]  = { (const float*)d_in[3], (const float*)d_in[7],  (const float*)d_in[11] };
    const float* asl[3] = { (const float*)d_in[4], (const float*)d_in[8],  (const float*)d_in[12] };
    const float* adl[3] = { (const float*)d_in[5], (const float*)d_in[9],  (const float*)d_in[13] };
    const float* bl[3]  = { (const float*)d_in[6], (const float*)d_in[10], (const float*)d_in[14] };
    const int din[3]  = {128, 64, 128};

    const float* d1w = (const float*)d_in[15]; const float* d1b = (const float*)d_in[16];
    const float* d2w = (const float*)d_in[17]; const float* d2b = (const float*)d_in[18];
    const float* d3w = (const float*)d_in[19]; const float* d3b = (const float*)d_in[20];
    const float* mw  = (const float*)d_in[21]; const float* mb  = (const float*)d_in[22];
    const float* d4w = (const float*)d_in[23]; const float* d4b = (const float*)d_in[24];
    const float* d5w = (const float*)d_in[25]; const float* d5b = (const float*)d_in[26];
    const float* d6w = (const float*)d_in[27]; const float* d6b = (const float*)d_in[28];
    const float* d7w = (const float*)d_in[29]; const float* d7b = (const float*)d_in[30];

    // -------- workspace carve --------
    float* ws = (float*)d_ws;
    size_t off = 0;
    float* Xbuf  = ws + off; off += (size_t)NN * 256;   // layer output / next input
    float* Hbuf  = ws + off; off += (size_t)NN * 256;   // transformed features
    float* sbuf  = ws + off; off += NN;
    float* tbuf  = ws + off; off += NN;
    unsigned* x1k = (unsigned*)(ws + off); off += NG * 256;
    float* x2    = ws + off; off += NG * 256;
    float* cnt   = ws + off; off += NG;
    float* z512  = ws + off; off += NG * 512;
    float* x3    = ws + off; off += NG * 256;
    float* tA    = ws + off; off += NG * 256;
    float* tB    = ws + off; off += NG * 256;
    float* gate  = ws + off; off += NG * 64;
    int* ip      = (int*)(ws + off);
    int* deg     = ip;               ip += NN;
    int* excl    = ip;               ip += NN;
    int* partials= ip;               ip += SCAN_B;
    int* rowptr  = ip;               ip += NN + 1;
    int* cursor  = ip;               ip += NN;
    int* srcsort = ip;               ip += NEP;

    const int nb = (NN + SCAN_B - 1) / SCAN_B;   // 196 <= 256

    // -------- CSR build (once; reused by all 3 layers) --------
    k_zero_int<<<(NN + 255) / 256, 256, 0, stream>>>(deg, NN);
    k_hist<<<(NEP + 255) / 256, 256, 0, stream>>>(dst, deg);
    k_scan1<<<nb, SCAN_B, 0, stream>>>(deg, excl, partials, NN);
    k_scan2<<<1, SCAN_B, 0, stream>>>(partials, nb);
    k_scan3<<<nb, SCAN_B, 0, stream>>>(excl, partials, rowptr, cursor, NN);
    k_scatter<<<(NEP + 255) / 256, 256, 0, stream>>>(src, dst, cursor, srcsort);

    // -------- three GAT layers --------
    for (int l = 0; l < 3; l++) {
        const float* X = (l == 0) ? x_in : Xbuf;
        dim3 gblk(64, 4);
        dim3 ggrd(1, NN / 16);   // NN % 16 == 0
        if (l == 0)      k_gemm_t<1><<<ggrd, gblk, 0, stream>>>(X, Wl[l], Hbuf, din[l]);
        else if (l == 1) k_gemm_t<2><<<ggrd, gblk, 0, stream>>>(X, Wl[l], Hbuf, din[l]);
        else             k_gemm_t<4><<<ggrd, gblk, 0, stream>>>(X, Wl[l], Hbuf, din[l]);
        int doo = 64 << l;
        k_proj<<<(NN * 64 + 255) / 256, 256, 0, stream>>>(Hbuf, asl[l], adl[l], sbuf, tbuf, doo);
        int agrid = (NN + 3) / 4;
        if (l == 0)      k_agg<64><<<agrid, 256, 0, stream>>>(rowptr, srcsort, sbuf, tbuf, Hbuf, bl[l], Xbuf);
        else if (l == 1) k_agg<128><<<agrid, 256, 0, stream>>>(rowptr, srcsort, sbuf, tbuf, Hbuf, bl[l], Xbuf);
        else             k_agg<256><<<agrid, 256, 0, stream>>>(rowptr, srcsort, sbuf, tbuf, Hbuf, bl[l], Xbuf);
    }

    // -------- pooling --------
    k_pool_init<<<(NG * 256 + 255) / 256, 256, 0, stream>>>(x1k, x2, cnt);
    k_pool<<<(NN * 64 + 255) / 256, 256, 0, stream>>>(Xbuf, batch, x1k, x2, cnt);
    k_buildz<<<(NG * 256 + 255) / 256, 256, 0, stream>>>(x1k, x2, cnt, z512, x3);

    // -------- dense tail --------
    k_dense<<<NG, 256, 0, stream>>>(z512, d1w, d1b, tA, 512, 256, 1);
    k_dense<<<NG, 128, 0, stream>>>(tA,   d2w, d2b, tB, 256, 128, 1);
    k_dense<<<NG,  64, 0, stream>>>(tB,   d3w, d3b, tA, 128,  64, 1);
    k_dense<<<NG,  64, 0, stream>>>(x3,   mw,  mb,  gate, 256, 64, 2);
    k_mul<<<(NG * 64 + 255) / 256, 256, 0, stream>>>(tA, gate, NG * 64);
    k_dense<<<NG,  64, 0, stream>>>(tA,   d4w, d4b, tB,  64,  64, 1);
    k_dense<<<NG, 128, 0, stream>>>(tB,   d5w, d5b, tA,  64, 128, 1);
    k_dense<<<NG, 256, 0, stream>>>(tA,   d6w, d6b, tB, 128, 256, 1);
    k_dense<<<NG, 128, 0, stream>>>(tB,   d7w, d7b, (float*)d_out, 256, 128, 0);
}

// Round 5
// 779.456 us; speedup vs baseline: 3.2726x; 1.4951x over previous
//
#include <hip/hip_runtime.h>
#include <hip/hip_bf16.h>
#include <math.h>

#define NN 50000      // nodes
#define NE 800000     // edges (without self loops)
#define NEP 850000    // edges + self loops
#define NG 64         // graphs
#define SCAN_B 256

// order-preserving float -> uint key (monotonic for all finite floats, incl +-0)
__device__ __forceinline__ unsigned fkey(float f) {
    unsigned u = __float_as_uint(f);
    return (u & 0x80000000u) ? ~u : (u | 0x80000000u);
}
__device__ __forceinline__ float fkey_inv(unsigned k) {
    return (k & 0x80000000u) ? __uint_as_float(k ^ 0x80000000u) : __uint_as_float(~k);
}

// ================= CSR build =================
__global__ void k_zero_int(int* __restrict__ p, int n) {
    int i = blockIdx.x * blockDim.x + threadIdx.x;
    if (i < n) p[i] = 0;
}

__global__ void k_hist(const int* __restrict__ dst, int* __restrict__ deg) {
    int i = blockIdx.x * blockDim.x + threadIdx.x;
    if (i >= NEP) return;
    int dv = (i < NE) ? dst[i] : (i - NE);
    atomicAdd(&deg[dv], 1);
}

__global__ void k_scan1(const int* __restrict__ deg, int* __restrict__ excl,
                        int* __restrict__ partials, int n) {
    __shared__ int sh[SCAN_B];
    int i = blockIdx.x * SCAN_B + threadIdx.x;
    int v = (i < n) ? deg[i] : 0;
    sh[threadIdx.x] = v;
    __syncthreads();
    for (int off = 1; off < SCAN_B; off <<= 1) {
        int t = (threadIdx.x >= off) ? sh[threadIdx.x - off] : 0;
        __syncthreads();
        sh[threadIdx.x] += t;
        __syncthreads();
    }
    if (i < n) excl[i] = sh[threadIdx.x] - v;
    if (threadIdx.x == SCAN_B - 1) partials[blockIdx.x] = sh[threadIdx.x];
}

__global__ void k_scan2(int* __restrict__ partials, int nb) {  // single block, nb <= 256
    __shared__ int sh[SCAN_B];
    int v = (threadIdx.x < nb) ? partials[threadIdx.x] : 0;
    sh[threadIdx.x] = v;
    __syncthreads();
    for (int off = 1; off < SCAN_B; off <<= 1) {
        int t = (threadIdx.x >= off) ? sh[threadIdx.x - off] : 0;
        __syncthreads();
        sh[threadIdx.x] += t;
        __syncthreads();
    }
    if (threadIdx.x < nb) partials[threadIdx.x] = sh[threadIdx.x] - v;
}

__global__ void k_scan3(const int* __restrict__ excl, const int* __restrict__ partials,
                        int* __restrict__ rowptr, int* __restrict__ cursor, int n) {
    int i = blockIdx.x * SCAN_B + threadIdx.x;
    if (i < n) {
        int r = excl[i] + partials[blockIdx.x];
        rowptr[i] = r;
        cursor[i] = r;
    }
    if (i == 0) rowptr[n] = NEP;
}

__global__ void k_scatter(const int* __restrict__ src, const int* __restrict__ dst,
                          int* __restrict__ cursor, int* __restrict__ srcsort) {
    int i = blockIdx.x * blockDim.x + threadIdx.x;
    if (i >= NEP) return;
    int sv = (i < NE) ? src[i] : (i - NE);
    int dv = (i < NE) ? dst[i] : (i - NE);
    int pos = atomicAdd(&cursor[dv], 1);
    srcsort[pos] = sv;
}

// ================= GEMM + fused projections =================
// H[NN,dout] = X[NN,din] @ W[din,dout]; s = H.asv, t = H.adv fused in epilogue.
// block (64,4): 16 rows/block, OPT outputs/thread (dout = 64*OPT), X tile in LDS.
template<int OPT>
__global__ void k_gemm_t(const float* __restrict__ X, const float* __restrict__ W,
                         float* __restrict__ H, const float* __restrict__ asv,
                         const float* __restrict__ adv, float* __restrict__ s,
                         float* __restrict__ t, int din) {
    const int dout = 64 * OPT;
    __shared__ float xs[16 * 128];
    int tx = threadIdx.x, ty = threadIdx.y;
    int tid = ty * 64 + tx;
    int n0 = blockIdx.y * 16;
    for (int idx = tid; idx < 16 * din; idx += 256)
        xs[idx] = X[(size_t)n0 * din + idx];   // 16 consecutive rows contiguous
    __syncthreads();
    int rbase = ty * 4;
    float acc[4][OPT];
#pragma unroll
    for (int r = 0; r < 4; r++)
#pragma unroll
        for (int o = 0; o < OPT; o++) acc[r][o] = 0.f;
    for (int k = 0; k < din; k++) {
        float w[OPT];
        if constexpr (OPT == 4) {
            float4 t4 = *(const float4*)(W + (size_t)k * dout + tx * 4);
            w[0] = t4.x; w[1] = t4.y; w[2] = t4.z; w[3] = t4.w;
        } else if constexpr (OPT == 2) {
            float2 t2 = *(const float2*)(W + (size_t)k * dout + tx * 2);
            w[0] = t2.x; w[1] = t2.y;
        } else {
            w[0] = W[(size_t)k * dout + tx];
        }
#pragma unroll
        for (int r = 0; r < 4; r++) {
            float xv = xs[(rbase + r) * din + k];
#pragma unroll
            for (int o = 0; o < OPT; o++) acc[r][o] += xv * w[o];
        }
    }
#pragma unroll
    for (int r = 0; r < 4; r++) {
        float* out = H + (size_t)(n0 + rbase + r) * dout + tx * OPT;
        if constexpr (OPT == 4) *(float4*)out = make_float4(acc[r][0], acc[r][1], acc[r][2], acc[r][3]);
        else if constexpr (OPT == 2) *(float2*)out = make_float2(acc[r][0], acc[r][1]);
        else out[0] = acc[r][0];
        // fused projection: wave (fixed ty) holds the whole row across tx
        float pa = 0.f, pb = 0.f;
#pragma unroll
        for (int o = 0; o < OPT; o++) {
            int og = tx * OPT + o;
            pa += acc[r][o] * asv[og];
            pb += acc[r][o] * adv[og];
        }
#pragma unroll
        for (int off = 32; off; off >>= 1) {
            pa += __shfl_xor(pa, off);
            pb += __shfl_xor(pb, off);
        }
        if (tx == 0) { s[n0 + rbase + r] = pa; t[n0 + rbase + r] = pb; }
    }
}

// ================= fused softmax + aggregation: wave per dst node =================
template<int DOUT>
__global__ void k_agg(const int* __restrict__ rowptr, const int* __restrict__ srcsort,
                      const float* __restrict__ s, const float* __restrict__ t,
                      const float* __restrict__ H, const float* __restrict__ bias,
                      float* __restrict__ OUT) {
    constexpr int R = DOUT / 64;
    int node = blockIdx.x * 4 + (threadIdx.x >> 6);
    int lane = threadIdx.x & 63;
    if (node >= NN) return;
    int beg = rowptr[node], end = rowptr[node + 1];
    float tn = t[node];
    float dsum = 0.f;
    for (int j = beg + lane; j < end; j += 64) {
        float e = s[srcsort[j]] + tn;
        e = (e > 0.f) ? e : 0.2f * e;
        dsum += expf(e);
    }
#pragma unroll
    for (int off = 32; off; off >>= 1) dsum += __shfl_xor(dsum, off);
    float inv = 1.f / dsum;   // self-loop guarantees dsum > 0
    float acc[R];
    if constexpr (R == 4) {
        float4 b4 = ((const float4*)bias)[lane];
        acc[0] = b4.x; acc[1] = b4.y; acc[2] = b4.z; acc[3] = b4.w;
    } else if constexpr (R == 2) {
        float2 b2 = ((const float2*)bias)[lane];
        acc[0] = b2.x; acc[1] = b2.y;
    } else {
        acc[0] = bias[lane];
    }
    for (int j = beg; j < end; j++) {
        int sv = srcsort[j];
        float e = s[sv] + tn;
        e = (e > 0.f) ? e : 0.2f * e;
        float alpha = expf(e) * inv;
        const float* hrow = H + (size_t)sv * DOUT;
        if constexpr (R == 4) {
            float4 v = ((const float4*)hrow)[lane];
            acc[0] += alpha * v.x; acc[1] += alpha * v.y;
            acc[2] += alpha * v.z; acc[3] += alpha * v.w;
        } else if constexpr (R == 2) {
            float2 v = ((const float2*)hrow)[lane];
            acc[0] += alpha * v.x; acc[1] += alpha * v.y;
        } else {
            acc[0] += alpha * hrow[lane];
        }
    }
    float* orow = OUT + (size_t)node * DOUT;
    if constexpr (R == 4) ((float4*)orow)[lane] = make_float4(acc[0], acc[1], acc[2], acc[3]);
    else if constexpr (R == 2) ((float2*)orow)[lane] = make_float2(acc[0], acc[1]);
    else orow[lane] = acc[0];
}

// ================= pooling =================
__global__ void k_pool_init(unsigned* __restrict__ x1k, float* __restrict__ x2, float* __restrict__ cnt) {
    int i = blockIdx.x * blockDim.x + threadIdx.x;
    if (i < NG * 256) { x1k[i] = 0u; x2[i] = 0.f; }
    if (i < NG) cnt[i] = 0.f;
}

// batch is SORTED: block = 256-node contiguous chunk, thread = feature column.
// Register-accumulate per graph segment; one atomic per (segment x feature).
__global__ void k_pool2(const float* __restrict__ H, const int* __restrict__ batch,
                        unsigned* __restrict__ x1k, float* __restrict__ x2,
                        float* __restrict__ cnt) {
    int c0 = blockIdx.x * 256;
    int o = threadIdx.x;
    int endn = min(c0 + 256, NN);
    int g = batch[c0];
    float mx = -INFINITY, sm = 0.f, cl = 0.f;
    for (int nd = c0; nd < endn; nd++) {
        int bg = batch[nd];                    // wave-uniform broadcast
        if (bg != g) {
            atomicMax(&x1k[g * 256 + o], fkey(mx));
            atomicAdd(&x2[g * 256 + o], sm);
            if (o == 0) atomicAdd(&cnt[g], cl);
            g = bg; mx = -INFINITY; sm = 0.f; cl = 0.f;
        }
        float hv = H[(size_t)nd * 256 + o];
        mx = fmaxf(mx, hv);
        sm += hv;
        cl += 1.f;
    }
    atomicMax(&x1k[g * 256 + o], fkey(mx));
    atomicAdd(&x2[g * 256 + o], sm);
    if (o == 0) atomicAdd(&cnt[g], cl);
}

// ================= fused dense tail: one block per graph =================
__global__ void k_tail(const unsigned* __restrict__ x1k, const float* __restrict__ x2,
                       const float* __restrict__ cnt,
                       const float* __restrict__ d1w, const float* __restrict__ d1b,
                       const float* __restrict__ d2w, const float* __restrict__ d2b,
                       const float* __restrict__ d3w, const float* __restrict__ d3b,
                       const float* __restrict__ mw,  const float* __restrict__ mb,
                       const float* __restrict__ d4w, const float* __restrict__ d4b,
                       const float* __restrict__ d5w, const float* __restrict__ d5b,
                       const float* __restrict__ d6w, const float* __restrict__ d6b,
                       const float* __restrict__ d7w, const float* __restrict__ d7b,
                       float* __restrict__ out) {
    __shared__ float z[512];    // d1 input, later d6 output (first 256)
    __shared__ float bufA[256];
    __shared__ float bufB[256];
    __shared__ float x3s[256];
    int g = blockIdx.x, o = threadIdx.x;   // 256 threads
    float c = fmaxf(cnt[g], 1.f);
    float sv = x2[(size_t)g * 256 + o];
    z[o] = fkey_inv(x1k[(size_t)g * 256 + o]);
    z[256 + o] = sv;
    x3s[o] = sv / c;
    __syncthreads();
    { // d1: 512 -> 256, relu
        float a = d1b[o];
        for (int k = 0; k < 512; k++) a += z[k] * d1w[(size_t)k * 256 + o];
        bufA[o] = fmaxf(a, 0.f);
    }
    __syncthreads();
    if (o < 128) { // d2: 256 -> 128, relu
        float a = d2b[o];
        for (int k = 0; k < 256; k++) a += bufA[k] * d2w[(size_t)k * 128 + o];
        bufB[o] = fmaxf(a, 0.f);
    }
    __syncthreads();
    if (o < 64) { // d3: 128 -> 64, relu
        float a = d3b[o];
        for (int k = 0; k < 128; k++) a += bufB[k] * d3w[(size_t)k * 64 + o];
        bufA[o] = fmaxf(a, 0.f);
    }
    __syncthreads();
    if (o < 64) { // gate: sigmoid(x3 @ mw + mb), applied to d3 output
        float a = mb[o];
        for (int k = 0; k < 256; k++) a += x3s[k] * mw[(size_t)k * 64 + o];
        bufA[o] *= 1.f / (1.f + expf(-a));
    }
    __syncthreads();
    if (o < 64) { // d4: 64 -> 64, relu
        float a = d4b[o];
        for (int k = 0; k < 64; k++) a += bufA[k] * d4w[(size_t)k * 64 + o];
        bufB[o] = fmaxf(a, 0.f);
    }
    __syncthreads();
    if (o < 128) { // d5: 64 -> 128, relu
        float a = d5b[o];
        for (int k = 0; k < 64; k++) a += bufB[k] * d5w[(size_t)k * 128 + o];
        bufA[o] = fmaxf(a, 0.f);
    }
    __syncthreads();
    { // d6: 128 -> 256, relu
        float a = d6b[o];
        for (int k = 0; k < 128; k++) a += bufA[k] * d6w[(size_t)k * 256 + o];
        z[o] = fmaxf(a, 0.f);
    }
    __syncthreads();
    if (o < 128) { // d7: 256 -> 128
        float a = d7b[o];
        for (int k = 0; k < 256; k++) a += z[k] * d7w[(size_t)k * 128 + o];
        out[(size_t)g * 128 + o] = a;
    }
}

// =====================================================================
extern "C" void kernel_launch(void* const* d_in, const int* in_sizes, int n_in,
                              void* d_out, int out_size, void* d_ws, size_t ws_size,
                              hipStream_t stream) {
    const float* x_in  = (const float*)d_in[0];
    const int*   ei    = (const int*)d_in[1];
    const int*   batch = (const int*)d_in[2];
    const int* src = ei;
    const int* dst = ei + NE;

    const float* Wl[3]  = { (const float*)d_in[3], (const float*)d_in[7],  (const float*)d_in[11] };
    const float* asl[3] = { (const float*)d_in[4], (const float*)d_in[8],  (const float*)d_in[12] };
    const float* adl[3] = { (const float*)d_in[5], (const float*)d_in[9],  (const float*)d_in[13] };
    const float* bl[3]  = { (const float*)d_in[6], (const float*)d_in[10], (const float*)d_in[14] };
    const int din[3]  = {128, 64, 128};

    const float* d1w = (const float*)d_in[15]; const float* d1b = (const float*)d_in[16];
    const float* d2w = (const float*)d_in[17]; const float* d2b = (const float*)d_in[18];
    const float* d3w = (const float*)d_in[19]; const float* d3b = (const float*)d_in[20];
    const float* mw  = (const float*)d_in[21]; const float* mb  = (const float*)d_in[22];
    const float* d4w = (const float*)d_in[23]; const float* d4b = (const float*)d_in[24];
    const float* d5w = (const float*)d_in[25]; const float* d5b = (const float*)d_in[26];
    const float* d6w = (const float*)d_in[27]; const float* d6b = (const float*)d_in[28];
    const float* d7w = (const float*)d_in[29]; const float* d7b = (const float*)d_in[30];

    // -------- workspace carve --------
    float* ws = (float*)d_ws;
    size_t off = 0;
    float* Xbuf  = ws + off; off += (size_t)NN * 256;   // layer output / next input
    float* Hbuf  = ws + off; off += (size_t)NN * 256;   // transformed features
    float* sbuf  = ws + off; off += NN;
    float* tbuf  = ws + off; off += NN;
    unsigned* x1k = (unsigned*)(ws + off); off += NG * 256;
    float* x2    = ws + off; off += NG * 256;
    float* cnt   = ws + off; off += NG;
    int* ip      = (int*)(ws + off);
    int* deg     = ip;               ip += NN;
    int* excl    = ip;               ip += NN;
    int* partials= ip;               ip += SCAN_B;
    int* rowptr  = ip;               ip += NN + 1;
    int* cursor  = ip;               ip += NN;
    int* srcsort = ip;               ip += NEP;

    const int nb = (NN + SCAN_B - 1) / SCAN_B;   // 196 <= 256

    // -------- CSR build (reused by all 3 layers) --------
    k_zero_int<<<(NN + 255) / 256, 256, 0, stream>>>(deg, NN);
    k_hist<<<(NEP + 255) / 256, 256, 0, stream>>>(dst, deg);
    k_scan1<<<nb, SCAN_B, 0, stream>>>(deg, excl, partials, NN);
    k_scan2<<<1, SCAN_B, 0, stream>>>(partials, nb);
    k_scan3<<<nb, SCAN_B, 0, stream>>>(excl, partials, rowptr, cursor, NN);
    k_scatter<<<(NEP + 255) / 256, 256, 0, stream>>>(src, dst, cursor, srcsort);

    // -------- three GAT layers --------
    for (int l = 0; l < 3; l++) {
        const float* X = (l == 0) ? x_in : Xbuf;
        dim3 gblk(64, 4);
        dim3 ggrd(1, NN / 16);   // NN % 16 == 0
        if (l == 0)      k_gemm_t<1><<<ggrd, gblk, 0, stream>>>(X, Wl[l], Hbuf, asl[l], adl[l], sbuf, tbuf, din[l]);
        else if (l == 1) k_gemm_t<2><<<ggrd, gblk, 0, stream>>>(X, Wl[l], Hbuf, asl[l], adl[l], sbuf, tbuf, din[l]);
        else             k_gemm_t<4><<<ggrd, gblk, 0, stream>>>(X, Wl[l], Hbuf, asl[l], adl[l], sbuf, tbuf, din[l]);
        int agrid = (NN + 3) / 4;
        if (l == 0)      k_agg<64><<<agrid, 256, 0, stream>>>(rowptr, srcsort, sbuf, tbuf, Hbuf, bl[l], Xbuf);
        else if (l == 1) k_agg<128><<<agrid, 256, 0, stream>>>(rowptr, srcsort, sbuf, tbuf, Hbuf, bl[l], Xbuf);
        else             k_agg<256><<<agrid, 256, 0, stream>>>(rowptr, srcsort, sbuf, tbuf, Hbuf, bl[l], Xbuf);
    }

    // -------- pooling + fused tail --------
    k_pool_init<<<(NG * 256 + 255) / 256, 256, 0, stream>>>(x1k, x2, cnt);
    k_pool2<<<(NN + 255) / 256, 256, 0, stream>>>(Xbuf, batch, x1k, x2, cnt);
    k_tail<<<NG, 256, 0, stream>>>(x1k, x2, cnt,
                                   d1w, d1b, d2w, d2b, d3w, d3b, mw, mb,
                                   d4w, d4b, d5w, d5b, d6w, d6b, d7w, d7b,
                                   (float*)d_out);
}

// Round 6
// 656.327 us; speedup vs baseline: 3.8866x; 1.1876x over previous
//
#include <hip/hip_runtime.h>
#include <hip/hip_bf16.h>
#include <math.h>

#define NN 50000      // nodes
#define NE 800000     // edges (without self loops)
#define NEP 850000    // edges + self loops
#define NG 64         // graphs
#define SCAN_B 256

typedef __hip_bfloat16 bf16;

__device__ __forceinline__ float bfu2f(unsigned short u) {
    return __uint_as_float((unsigned)u << 16);
}
__device__ __forceinline__ unsigned short f2bfu(float f) {
    __hip_bfloat16 h = __float2bfloat16(f);   // RTNE
    union { __hip_bfloat16 h; unsigned short u; } c; c.h = h; return c.u;
}

// order-preserving float -> uint key
__device__ __forceinline__ unsigned fkey(float f) {
    unsigned u = __float_as_uint(f);
    return (u & 0x80000000u) ? ~u : (u | 0x80000000u);
}
__device__ __forceinline__ float fkey_inv(unsigned k) {
    return (k & 0x80000000u) ? __uint_as_float(k ^ 0x80000000u) : __uint_as_float(~k);
}

// ================= CSR build =================
__global__ void k_zero_int(int* __restrict__ p, int n) {
    int i = blockIdx.x * blockDim.x + threadIdx.x;
    if (i < n) p[i] = 0;
}

__global__ void k_hist(const int* __restrict__ dst, int* __restrict__ deg) {
    int i = blockIdx.x * blockDim.x + threadIdx.x;
    if (i >= NEP) return;
    int dv = (i < NE) ? dst[i] : (i - NE);
    atomicAdd(&deg[dv], 1);
}

__global__ void k_scan1(const int* __restrict__ deg, int* __restrict__ excl,
                        int* __restrict__ partials, int n) {
    __shared__ int sh[SCAN_B];
    int i = blockIdx.x * SCAN_B + threadIdx.x;
    int v = (i < n) ? deg[i] : 0;
    sh[threadIdx.x] = v;
    __syncthreads();
    for (int off = 1; off < SCAN_B; off <<= 1) {
        int t = (threadIdx.x >= off) ? sh[threadIdx.x - off] : 0;
        __syncthreads();
        sh[threadIdx.x] += t;
        __syncthreads();
    }
    if (i < n) excl[i] = sh[threadIdx.x] - v;
    if (threadIdx.x == SCAN_B - 1) partials[blockIdx.x] = sh[threadIdx.x];
}

__global__ void k_scan2(int* __restrict__ partials, int nb) {  // single block
    __shared__ int sh[SCAN_B];
    int v = (threadIdx.x < nb) ? partials[threadIdx.x] : 0;
    sh[threadIdx.x] = v;
    __syncthreads();
    for (int off = 1; off < SCAN_B; off <<= 1) {
        int t = (threadIdx.x >= off) ? sh[threadIdx.x - off] : 0;
        __syncthreads();
        sh[threadIdx.x] += t;
        __syncthreads();
    }
    if (threadIdx.x < nb) partials[threadIdx.x] = sh[threadIdx.x] - v;
}

__global__ void k_scan3(const int* __restrict__ excl, const int* __restrict__ partials,
                        int* __restrict__ rowptr, int* __restrict__ cursor, int n) {
    int i = blockIdx.x * SCAN_B + threadIdx.x;
    if (i < n) {
        int r = excl[i] + partials[blockIdx.x];
        rowptr[i] = r;
        cursor[i] = r;
    }
    if (i == 0) rowptr[n] = NEP;
}

__global__ void k_scatter(const int* __restrict__ src, const int* __restrict__ dst,
                          int* __restrict__ cursor, int* __restrict__ srcsort) {
    int i = blockIdx.x * blockDim.x + threadIdx.x;
    if (i >= NEP) return;
    int sv = (i < NE) ? src[i] : (i - NE);
    int dv = (i < NE) ? dst[i] : (i - NE);
    int pos = atomicAdd(&cursor[dv], 1);
    srcsort[pos] = sv;
}

// ================= GEMM + fused projections, bf16 H output =================
// Hb[NN,dout](bf16) = X[NN,din] @ W[din,dout]; s = H.asv, t = H.adv fused (f32).
// block (64,4): 16 rows/block, OPT outputs/thread (dout = 64*OPT).
template<int OPT>
__global__ void k_gemm_t(const float* __restrict__ X, const float* __restrict__ W,
                         unsigned short* __restrict__ Hb, const float* __restrict__ asv,
                         const float* __restrict__ adv, float* __restrict__ s,
                         float* __restrict__ t, int din) {
    const int dout = 64 * OPT;
    __shared__ float xs[16 * 128];
    int tx = threadIdx.x, ty = threadIdx.y;
    int tid = ty * 64 + tx;
    int n0 = blockIdx.y * 16;
    for (int idx = tid; idx < 16 * din; idx += 256)
        xs[idx] = X[(size_t)n0 * din + idx];
    __syncthreads();
    int rbase = ty * 4;
    float acc[4][OPT];
#pragma unroll
    for (int r = 0; r < 4; r++)
#pragma unroll
        for (int o = 0; o < OPT; o++) acc[r][o] = 0.f;
    for (int k = 0; k < din; k++) {
        float w[OPT];
        if constexpr (OPT == 4) {
            float4 t4 = *(const float4*)(W + (size_t)k * dout + tx * 4);
            w[0] = t4.x; w[1] = t4.y; w[2] = t4.z; w[3] = t4.w;
        } else if constexpr (OPT == 2) {
            float2 t2 = *(const float2*)(W + (size_t)k * dout + tx * 2);
            w[0] = t2.x; w[1] = t2.y;
        } else {
            w[0] = W[(size_t)k * dout + tx];
        }
#pragma unroll
        for (int r = 0; r < 4; r++) {
            float xv = xs[(rbase + r) * din + k];
#pragma unroll
            for (int o = 0; o < OPT; o++) acc[r][o] += xv * w[o];
        }
    }
#pragma unroll
    for (int r = 0; r < 4; r++) {
        unsigned short* out = Hb + (size_t)(n0 + rbase + r) * dout + tx * OPT;
        if constexpr (OPT == 4) {
            ushort4 u;
            u.x = f2bfu(acc[r][0]); u.y = f2bfu(acc[r][1]);
            u.z = f2bfu(acc[r][2]); u.w = f2bfu(acc[r][3]);
            *(ushort4*)out = u;
        } else if constexpr (OPT == 2) {
            ushort2 u; u.x = f2bfu(acc[r][0]); u.y = f2bfu(acc[r][1]);
            *(ushort2*)out = u;
        } else {
            out[0] = f2bfu(acc[r][0]);
        }
        // fused projection from f32 accumulators
        float pa = 0.f, pb = 0.f;
#pragma unroll
        for (int o = 0; o < OPT; o++) {
            int og = tx * OPT + o;
            pa += acc[r][o] * asv[og];
            pb += acc[r][o] * adv[og];
        }
#pragma unroll
        for (int off = 32; off; off >>= 1) {
            pa += __shfl_xor(pa, off);
            pb += __shfl_xor(pb, off);
        }
        if (tx == 0) { s[n0 + rbase + r] = pa; t[n0 + rbase + r] = pb; }
    }
}

// ================= fused softmax + aggregation: wave per dst node =================
// bf16 gather, f32 accumulate. Chunked-shuffle alphas (no redundant expf).
template<int DOUT>
__global__ void k_agg(const int* __restrict__ rowptr, const int* __restrict__ srcsort,
                      const float* __restrict__ s, const float* __restrict__ t,
                      const unsigned short* __restrict__ Hb, const float* __restrict__ bias,
                      float* __restrict__ OUT) {
    constexpr int R = DOUT / 64;   // elements per lane
    int node = blockIdx.x * 4 + (threadIdx.x >> 6);
    int lane = threadIdx.x & 63;
    if (node >= NN) return;
    int beg = rowptr[node], end = rowptr[node + 1];
    float tn = t[node];
    // phase 1: denominator
    float dsum = 0.f;
    for (int j = beg + lane; j < end; j += 64) {
        float e = s[srcsort[j]] + tn;
        e = (e > 0.f) ? e : 0.2f * e;
        dsum += expf(e);
    }
#pragma unroll
    for (int off = 32; off; off >>= 1) dsum += __shfl_xor(dsum, off);
    float inv = 1.f / dsum;   // self-loop guarantees dsum > 0
    // phase 2: chunked gather; lane q computes alpha for edge cbeg+q, broadcast by shfl
    float acc[R];
#pragma unroll
    for (int o = 0; o < R; o++) acc[o] = bias[lane * R + o];
    for (int cbeg = beg; cbeg < end; cbeg += 64) {
        int j = cbeg + lane;
        float ex = 0.f; int sv = 0;
        if (j < end) {
            sv = srcsort[j];
            float e = s[sv] + tn;
            e = (e > 0.f) ? e : 0.2f * e;
            ex = expf(e) * inv;
        }
        int cnt = min(64, end - cbeg);
        for (int q = 0; q < cnt; q++) {
            float alpha = __shfl(ex, q);
            int svq = __shfl(sv, q);
            const unsigned short* hrow = Hb + (size_t)svq * DOUT + lane * R;
            if constexpr (R == 4) {
                ushort4 u = *(const ushort4*)hrow;
                acc[0] += alpha * bfu2f(u.x);
                acc[1] += alpha * bfu2f(u.y);
                acc[2] += alpha * bfu2f(u.z);
                acc[3] += alpha * bfu2f(u.w);
            } else if constexpr (R == 2) {
                ushort2 u = *(const ushort2*)hrow;
                acc[0] += alpha * bfu2f(u.x);
                acc[1] += alpha * bfu2f(u.y);
            } else {
                acc[0] += alpha * bfu2f(hrow[0]);
            }
        }
    }
    float* orow = OUT + (size_t)node * DOUT + lane * R;
    if constexpr (R == 4) *(float4*)orow = make_float4(acc[0], acc[1], acc[2], acc[3]);
    else if constexpr (R == 2) *(float2*)orow = make_float2(acc[0], acc[1]);
    else orow[0] = acc[0];
}

// ================= pooling =================
__global__ void k_pool_init(unsigned* __restrict__ x1k, float* __restrict__ x2, float* __restrict__ cnt) {
    int i = blockIdx.x * blockDim.x + threadIdx.x;
    if (i < NG * 256) { x1k[i] = 0u; x2[i] = 0.f; }
    if (i < NG) cnt[i] = 0.f;
}

// batch is SORTED: block = 256-node chunk, thread = feature column.
__global__ void k_pool2(const float* __restrict__ H, const int* __restrict__ batch,
                        unsigned* __restrict__ x1k, float* __restrict__ x2,
                        float* __restrict__ cnt) {
    int c0 = blockIdx.x * 256;
    int o = threadIdx.x;
    int endn = min(c0 + 256, NN);
    int g = batch[c0];
    float mx = -INFINITY, sm = 0.f, cl = 0.f;
    for (int nd = c0; nd < endn; nd++) {
        int bg = batch[nd];
        if (bg != g) {
            atomicMax(&x1k[g * 256 + o], fkey(mx));
            atomicAdd(&x2[g * 256 + o], sm);
            if (o == 0) atomicAdd(&cnt[g], cl);
            g = bg; mx = -INFINITY; sm = 0.f; cl = 0.f;
        }
        float hv = H[(size_t)nd * 256 + o];
        mx = fmaxf(mx, hv);
        sm += hv;
        cl += 1.f;
    }
    atomicMax(&x1k[g * 256 + o], fkey(mx));
    atomicAdd(&x2[g * 256 + o], sm);
    if (o == 0) atomicAdd(&cnt[g], cl);
}

// ================= fused dense tail: one block per graph =================
__global__ void k_tail(const unsigned* __restrict__ x1k, const float* __restrict__ x2,
                       const float* __restrict__ cnt,
                       const float* __restrict__ d1w, const float* __restrict__ d1b,
                       const float* __restrict__ d2w, const float* __restrict__ d2b,
                       const float* __restrict__ d3w, const float* __restrict__ d3b,
                       const float* __restrict__ mw,  const float* __restrict__ mb,
                       const float* __restrict__ d4w, const float* __restrict__ d4b,
                       const float* __restrict__ d5w, const float* __restrict__ d5b,
                       const float* __restrict__ d6w, const float* __restrict__ d6b,
                       const float* __restrict__ d7w, const float* __restrict__ d7b,
                       float* __restrict__ out) {
    __shared__ float z[512];
    __shared__ float bufA[256];
    __shared__ float bufB[256];
    __shared__ float x3s[256];
    int g = blockIdx.x, o = threadIdx.x;   // 256 threads
    float c = fmaxf(cnt[g], 1.f);
    float sv = x2[(size_t)g * 256 + o];
    z[o] = fkey_inv(x1k[(size_t)g * 256 + o]);
    z[256 + o] = sv;
    x3s[o] = sv / c;
    __syncthreads();
    { // d1: 512 -> 256, relu
        float a = d1b[o];
        for (int k = 0; k < 512; k++) a += z[k] * d1w[(size_t)k * 256 + o];
        bufA[o] = fmaxf(a, 0.f);
    }
    __syncthreads();
    if (o < 128) { // d2
        float a = d2b[o];
        for (int k = 0; k < 256; k++) a += bufA[k] * d2w[(size_t)k * 128 + o];
        bufB[o] = fmaxf(a, 0.f);
    }
    __syncthreads();
    if (o < 64) { // d3
        float a = d3b[o];
        for (int k = 0; k < 128; k++) a += bufB[k] * d3w[(size_t)k * 64 + o];
        bufA[o] = fmaxf(a, 0.f);
    }
    __syncthreads();
    if (o < 64) { // sigmoid gate
        float a = mb[o];
        for (int k = 0; k < 256; k++) a += x3s[k] * mw[(size_t)k * 64 + o];
        bufA[o] *= 1.f / (1.f + expf(-a));
    }
    __syncthreads();
    if (o < 64) { // d4
        float a = d4b[o];
        for (int k = 0; k < 64; k++) a += bufA[k] * d4w[(size_t)k * 64 + o];
        bufB[o] = fmaxf(a, 0.f);
    }
    __syncthreads();
    if (o < 128) { // d5
        float a = d5b[o];
        for (int k = 0; k < 64; k++) a += bufB[k] * d5w[(size_t)k * 128 + o];
        bufA[o] = fmaxf(a, 0.f);
    }
    __syncthreads();
    { // d6
        float a = d6b[o];
        for (int k = 0; k < 128; k++) a += bufA[k] * d6w[(size_t)k * 256 + o];
        z[o] = fmaxf(a, 0.f);
    }
    __syncthreads();
    if (o < 128) { // d7
        float a = d7b[o];
        for (int k = 0; k < 256; k++) a += z[k] * d7w[(size_t)k * 128 + o];
        out[(size_t)g * 128 + o] = a;
    }
}

// =====================================================================
extern "C" void kernel_launch(void* const* d_in, const int* in_sizes, int n_in,
                              void* d_out, int out_size, void* d_ws, size_t ws_size,
                              hipStream_t stream) {
    const float* x_in  = (const float*)d_in[0];
    const int*   ei    = (const int*)d_in[1];
    const int*   batch = (const int*)d_in[2];
    const int* src = ei;
    const int* dst = ei + NE;

    const float* Wl[3]  = { (const float*)d_in[3], (const float*)d_in[7],  (const float*)d_in[11] };
    const float* asl[3] = { (const float*)d_in[4], (const float*)d_in[8],  (const float*)d_in[12] };
    const float* adl[3] = { (const float*)d_in[5], (const float*)d_in[9],  (const float*)d_in[13] };
    const float* bl[3]  = { (const float*)d_in[6], (const float*)d_in[10], (const float*)d_in[14] };
    const int din[3]  = {128, 64, 128};

    const float* d1w = (const float*)d_in[15]; const float* d1b = (const float*)d_in[16];
    const float* d2w = (const float*)d_in[17]; const float* d2b = (const float*)d_in[18];
    const float* d3w = (const float*)d_in[19]; const float* d3b = (const float*)d_in[20];
    const float* mw  = (const float*)d_in[21]; const float* mb  = (const float*)d_in[22];
    const float* d4w = (const float*)d_in[23]; const float* d4b = (const float*)d_in[24];
    const float* d5w = (const float*)d_in[25]; const float* d5b = (const float*)d_in[26];
    const float* d6w = (const float*)d_in[27]; const float* d6b = (const float*)d_in[28];
    const float* d7w = (const float*)d_in[29]; const float* d7b = (const float*)d_in[30];

    // -------- workspace carve --------
    float* ws = (float*)d_ws;
    size_t off = 0;
    float* Xbuf  = ws + off; off += (size_t)NN * 256;       // layer output / next input (f32)
    unsigned short* Hb = (unsigned short*)(ws + off); off += (size_t)NN * 128;  // bf16 H (NN*256*2B)
    float* sbuf  = ws + off; off += NN;
    float* tbuf  = ws + off; off += NN;
    unsigned* x1k = (unsigned*)(ws + off); off += NG * 256;
    float* x2    = ws + off; off += NG * 256;
    float* cnt   = ws + off; off += NG;
    int* ip      = (int*)(ws + off);
    int* deg     = ip;               ip += NN;
    int* excl    = ip;               ip += NN;
    int* partials= ip;               ip += SCAN_B;
    int* rowptr  = ip;               ip += NN + 1;
    int* cursor  = ip;               ip += NN;
    int* srcsort = ip;               ip += NEP;

    const int nb = (NN + SCAN_B - 1) / SCAN_B;

    // -------- CSR build (reused by all 3 layers) --------
    k_zero_int<<<(NN + 255) / 256, 256, 0, stream>>>(deg, NN);
    k_hist<<<(NEP + 255) / 256, 256, 0, stream>>>(dst, deg);
    k_scan1<<<nb, SCAN_B, 0, stream>>>(deg, excl, partials, NN);
    k_scan2<<<1, SCAN_B, 0, stream>>>(partials, nb);
    k_scan3<<<nb, SCAN_B, 0, stream>>>(excl, partials, rowptr, cursor, NN);
    k_scatter<<<(NEP + 255) / 256, 256, 0, stream>>>(src, dst, cursor, srcsort);

    // -------- three GAT layers --------
    for (int l = 0; l < 3; l++) {
        const float* X = (l == 0) ? x_in : Xbuf;
        dim3 gblk(64, 4);
        dim3 ggrd(1, NN / 16);
        if (l == 0)      k_gemm_t<1><<<ggrd, gblk, 0, stream>>>(X, Wl[l], Hb, asl[l], adl[l], sbuf, tbuf, din[l]);
        else if (l == 1) k_gemm_t<2><<<ggrd, gblk, 0, stream>>>(X, Wl[l], Hb, asl[l], adl[l], sbuf, tbuf, din[l]);
        else             k_gemm_t<4><<<ggrd, gblk, 0, stream>>>(X, Wl[l], Hb, asl[l], adl[l], sbuf, tbuf, din[l]);
        int agrid = (NN + 3) / 4;
        if (l == 0)      k_agg<64><<<agrid, 256, 0, stream>>>(rowptr, srcsort, sbuf, tbuf, Hb, bl[l], Xbuf);
        else if (l == 1) k_agg<128><<<agrid, 256, 0, stream>>>(rowptr, srcsort, sbuf, tbuf, Hb, bl[l], Xbuf);
        else             k_agg<256><<<agrid, 256, 0, stream>>>(rowptr, srcsort, sbuf, tbuf, Hb, bl[l], Xbuf);
    }

    // -------- pooling + fused tail --------
    k_pool_init<<<(NG * 256 + 255) / 256, 256, 0, stream>>>(x1k, x2, cnt);
    k_pool2<<<(NN + 255) / 256, 256, 0, stream>>>(Xbuf, batch, x1k, x2, cnt);
    k_tail<<<NG, 256, 0, stream>>>(x1k, x2, cnt,
                                   d1w, d1b, d2w, d2b, d3w, d3b, mw, mb,
                                   d4w, d4b, d5w, d5b, d6w, d6b, d7w, d7b,
                                   (float*)d_out);
}

// Round 7
// 516.299 us; speedup vs baseline: 4.9407x; 1.2712x over previous
//
#include <hip/hip_runtime.h>
#include <hip/hip_bf16.h>
#include <math.h>

#define NN 50000      // nodes
#define NE 800000     // edges (without self loops)
#define NEP 850000    // edges + self loops
#define NG 64         // graphs
#define SCAN_B 256

__device__ __forceinline__ float bfu2f(unsigned short u) {
    return __uint_as_float((unsigned)u << 16);
}
__device__ __forceinline__ unsigned short f2bfu(float f) {
    __hip_bfloat16 h = __float2bfloat16(f);   // RTNE
    union { __hip_bfloat16 h; unsigned short u; } c; c.h = h; return c.u;
}

// order-preserving float -> uint key
__device__ __forceinline__ unsigned fkey(float f) {
    unsigned u = __float_as_uint(f);
    return (u & 0x80000000u) ? ~u : (u | 0x80000000u);
}
__device__ __forceinline__ float fkey_inv(unsigned k) {
    return (k & 0x80000000u) ? __uint_as_float(k ^ 0x80000000u) : __uint_as_float(~k);
}

// ================= CSR build =================
__global__ void k_zero_int(int* __restrict__ p, int n) {
    int i = blockIdx.x * blockDim.x + threadIdx.x;
    if (i < n) p[i] = 0;
}

__global__ void k_hist(const int* __restrict__ dst, int* __restrict__ deg) {
    int i = blockIdx.x * blockDim.x + threadIdx.x;
    if (i >= NEP) return;
    int dv = (i < NE) ? dst[i] : (i - NE);
    atomicAdd(&deg[dv], 1);
}

__global__ void k_scan1(const int* __restrict__ deg, int* __restrict__ excl,
                        int* __restrict__ partials, int n) {
    __shared__ int sh[SCAN_B];
    int i = blockIdx.x * SCAN_B + threadIdx.x;
    int v = (i < n) ? deg[i] : 0;
    sh[threadIdx.x] = v;
    __syncthreads();
    for (int off = 1; off < SCAN_B; off <<= 1) {
        int t = (threadIdx.x >= off) ? sh[threadIdx.x - off] : 0;
        __syncthreads();
        sh[threadIdx.x] += t;
        __syncthreads();
    }
    if (i < n) excl[i] = sh[threadIdx.x] - v;
    if (threadIdx.x == SCAN_B - 1) partials[blockIdx.x] = sh[threadIdx.x];
}

__global__ void k_scan2(int* __restrict__ partials, int nb) {  // single block
    __shared__ int sh[SCAN_B];
    int v = (threadIdx.x < nb) ? partials[threadIdx.x] : 0;
    sh[threadIdx.x] = v;
    __syncthreads();
    for (int off = 1; off < SCAN_B; off <<= 1) {
        int t = (threadIdx.x >= off) ? sh[threadIdx.x - off] : 0;
        __syncthreads();
        sh[threadIdx.x] += t;
        __syncthreads();
    }
    if (threadIdx.x < nb) partials[threadIdx.x] = sh[threadIdx.x] - v;
}

__global__ void k_scan3(const int* __restrict__ excl, const int* __restrict__ partials,
                        int* __restrict__ rowptr, int* __restrict__ cursor, int n) {
    int i = blockIdx.x * SCAN_B + threadIdx.x;
    if (i < n) {
        int r = excl[i] + partials[blockIdx.x];
        rowptr[i] = r;
        cursor[i] = r;
    }
    if (i == 0) rowptr[n] = NEP;
}

__global__ void k_scatter(const int* __restrict__ src, const int* __restrict__ dst,
                          int* __restrict__ cursor, int* __restrict__ srcsort) {
    int i = blockIdx.x * blockDim.x + threadIdx.x;
    if (i >= NEP) return;
    int sv = (i < NE) ? src[i] : (i - NE);
    int dv = (i < NE) ? dst[i] : (i - NE);
    int pos = atomicAdd(&cursor[dv], 1);
    srcsort[pos] = sv;
}

// ================= GEMM + fused projections, bf16 H output =================
template<int OPT>
__global__ void k_gemm_t(const float* __restrict__ X, const float* __restrict__ W,
                         unsigned short* __restrict__ Hb, const float* __restrict__ asv,
                         const float* __restrict__ adv, float* __restrict__ s,
                         float* __restrict__ t, int din) {
    const int dout = 64 * OPT;
    __shared__ float xs[16 * 128];
    int tx = threadIdx.x, ty = threadIdx.y;
    int tid = ty * 64 + tx;
    int n0 = blockIdx.y * 16;
    for (int idx = tid; idx < 16 * din; idx += 256)
        xs[idx] = X[(size_t)n0 * din + idx];
    __syncthreads();
    int rbase = ty * 4;
    float acc[4][OPT];
#pragma unroll
    for (int r = 0; r < 4; r++)
#pragma unroll
        for (int o = 0; o < OPT; o++) acc[r][o] = 0.f;
    for (int k = 0; k < din; k++) {
        float w[OPT];
        if constexpr (OPT == 4) {
            float4 t4 = *(const float4*)(W + (size_t)k * dout + tx * 4);
            w[0] = t4.x; w[1] = t4.y; w[2] = t4.z; w[3] = t4.w;
        } else if constexpr (OPT == 2) {
            float2 t2 = *(const float2*)(W + (size_t)k * dout + tx * 2);
            w[0] = t2.x; w[1] = t2.y;
        } else {
            w[0] = W[(size_t)k * dout + tx];
        }
#pragma unroll
        for (int r = 0; r < 4; r++) {
            float xv = xs[(rbase + r) * din + k];
#pragma unroll
            for (int o = 0; o < OPT; o++) acc[r][o] += xv * w[o];
        }
    }
#pragma unroll
    for (int r = 0; r < 4; r++) {
        unsigned short* out = Hb + (size_t)(n0 + rbase + r) * dout + tx * OPT;
        if constexpr (OPT == 4) {
            ushort4 u;
            u.x = f2bfu(acc[r][0]); u.y = f2bfu(acc[r][1]);
            u.z = f2bfu(acc[r][2]); u.w = f2bfu(acc[r][3]);
            *(ushort4*)out = u;
        } else if constexpr (OPT == 2) {
            ushort2 u; u.x = f2bfu(acc[r][0]); u.y = f2bfu(acc[r][1]);
            *(ushort2*)out = u;
        } else {
            out[0] = f2bfu(acc[r][0]);
        }
        float pa = 0.f, pb = 0.f;
#pragma unroll
        for (int o = 0; o < OPT; o++) {
            int og = tx * OPT + o;
            pa += acc[r][o] * asv[og];
            pb += acc[r][o] * adv[og];
        }
#pragma unroll
        for (int off = 32; off; off >>= 1) {
            pa += __shfl_xor(pa, off);
            pb += __shfl_xor(pb, off);
        }
        if (tx == 0) { s[n0 + rbase + r] = pa; t[n0 + rbase + r] = pb; }
    }
}

// ================= fused softmax + aggregation: wave per dst node =================
// Phase-1 registers reused for chunk 0; 4x-unrolled gather for MLP.
template<int DOUT>
__global__ void k_agg(const int* __restrict__ rowptr, const int* __restrict__ srcsort,
                      const float* __restrict__ s, const float* __restrict__ t,
                      const unsigned short* __restrict__ Hb, const float* __restrict__ bias,
                      float* __restrict__ OUT) {
    constexpr int R = DOUT / 64;
    int node = blockIdx.x * 4 + (threadIdx.x >> 6);
    int lane = threadIdx.x & 63;
    if (node >= NN) return;
    int beg = rowptr[node], end = rowptr[node + 1];
    float tn = t[node];
    // phase 1: denominator; keep first-chunk values in registers
    int j0 = beg + lane;
    float ex0 = 0.f; int sv0 = 0;
    if (j0 < end) {
        sv0 = srcsort[j0];
        float e = s[sv0] + tn;
        e = (e > 0.f) ? e : 0.2f * e;
        ex0 = expf(e);
    }
    float dsum = ex0;
    for (int j = j0 + 64; j < end; j += 64) {
        float e = s[srcsort[j]] + tn;
        e = (e > 0.f) ? e : 0.2f * e;
        dsum += expf(e);
    }
#pragma unroll
    for (int off = 32; off; off >>= 1) dsum += __shfl_xor(dsum, off);
    float inv = 1.f / dsum;   // self-loop guarantees dsum > 0
    float acc[R];
#pragma unroll
    for (int o = 0; o < R; o++) acc[o] = bias[lane * R + o];

    auto gather = [&](float exv, int svv, int cnt) {
        int q = 0;
        for (; q + 4 <= cnt; q += 4) {
            float a0 = __shfl(exv, q),     a1 = __shfl(exv, q + 1);
            float a2 = __shfl(exv, q + 2), a3 = __shfl(exv, q + 3);
            int i0 = __shfl(svv, q),     i1 = __shfl(svv, q + 1);
            int i2 = __shfl(svv, q + 2), i3 = __shfl(svv, q + 3);
            if constexpr (R == 4) {
                ushort4 u0 = *(const ushort4*)(Hb + (size_t)i0 * DOUT + lane * 4);
                ushort4 u1 = *(const ushort4*)(Hb + (size_t)i1 * DOUT + lane * 4);
                ushort4 u2 = *(const ushort4*)(Hb + (size_t)i2 * DOUT + lane * 4);
                ushort4 u3 = *(const ushort4*)(Hb + (size_t)i3 * DOUT + lane * 4);
                acc[0] += a0 * bfu2f(u0.x); acc[1] += a0 * bfu2f(u0.y);
                acc[2] += a0 * bfu2f(u0.z); acc[3] += a0 * bfu2f(u0.w);
                acc[0] += a1 * bfu2f(u1.x); acc[1] += a1 * bfu2f(u1.y);
                acc[2] += a1 * bfu2f(u1.z); acc[3] += a1 * bfu2f(u1.w);
                acc[0] += a2 * bfu2f(u2.x); acc[1] += a2 * bfu2f(u2.y);
                acc[2] += a2 * bfu2f(u2.z); acc[3] += a2 * bfu2f(u2.w);
                acc[0] += a3 * bfu2f(u3.x); acc[1] += a3 * bfu2f(u3.y);
                acc[2] += a3 * bfu2f(u3.z); acc[3] += a3 * bfu2f(u3.w);
            } else if constexpr (R == 2) {
                ushort2 u0 = *(const ushort2*)(Hb + (size_t)i0 * DOUT + lane * 2);
                ushort2 u1 = *(const ushort2*)(Hb + (size_t)i1 * DOUT + lane * 2);
                ushort2 u2 = *(const ushort2*)(Hb + (size_t)i2 * DOUT + lane * 2);
                ushort2 u3 = *(const ushort2*)(Hb + (size_t)i3 * DOUT + lane * 2);
                acc[0] += a0 * bfu2f(u0.x); acc[1] += a0 * bfu2f(u0.y);
                acc[0] += a1 * bfu2f(u1.x); acc[1] += a1 * bfu2f(u1.y);
                acc[0] += a2 * bfu2f(u2.x); acc[1] += a2 * bfu2f(u2.y);
                acc[0] += a3 * bfu2f(u3.x); acc[1] += a3 * bfu2f(u3.y);
            } else {
                unsigned short u0 = Hb[(size_t)i0 * DOUT + lane];
                unsigned short u1 = Hb[(size_t)i1 * DOUT + lane];
                unsigned short u2 = Hb[(size_t)i2 * DOUT + lane];
                unsigned short u3 = Hb[(size_t)i3 * DOUT + lane];
                acc[0] += a0 * bfu2f(u0) + a1 * bfu2f(u1) + a2 * bfu2f(u2) + a3 * bfu2f(u3);
            }
        }
        for (; q < cnt; q++) {
            float a = __shfl(exv, q);
            int  i = __shfl(svv, q);
            const unsigned short* hrow = Hb + (size_t)i * DOUT + lane * R;
            if constexpr (R == 4) {
                ushort4 u = *(const ushort4*)hrow;
                acc[0] += a * bfu2f(u.x); acc[1] += a * bfu2f(u.y);
                acc[2] += a * bfu2f(u.z); acc[3] += a * bfu2f(u.w);
            } else if constexpr (R == 2) {
                ushort2 u = *(const ushort2*)hrow;
                acc[0] += a * bfu2f(u.x); acc[1] += a * bfu2f(u.y);
            } else {
                acc[0] += a * bfu2f(hrow[0]);
            }
        }
    };

    // chunk 0 from saved registers (covers all edges for deg <= 64)
    gather(ex0 * inv, sv0, min(64, end - beg));
    // remaining chunks
    for (int cbeg = beg + 64; cbeg < end; cbeg += 64) {
        int j = cbeg + lane;
        float ex = 0.f; int sv = 0;
        if (j < end) {
            sv = srcsort[j];
            float e = s[sv] + tn;
            e = (e > 0.f) ? e : 0.2f * e;
            ex = expf(e) * inv;
        }
        gather(ex, sv, min(64, end - cbeg));
    }

    float* orow = OUT + (size_t)node * DOUT + lane * R;
    if constexpr (R == 4) *(float4*)orow = make_float4(acc[0], acc[1], acc[2], acc[3]);
    else if constexpr (R == 2) *(float2*)orow = make_float2(acc[0], acc[1]);
    else orow[0] = acc[0];
}

// ================= pooling =================
__global__ void k_pool_init(unsigned* __restrict__ x1k, float* __restrict__ x2, float* __restrict__ cnt) {
    int i = blockIdx.x * blockDim.x + threadIdx.x;
    if (i < NG * 256) { x1k[i] = 0u; x2[i] = 0.f; }
    if (i < NG) cnt[i] = 0.f;
}

// batch is SORTED: block = 64-node chunk (782 blocks for TLP), thread = feature col.
__global__ void k_pool2(const float* __restrict__ H, const int* __restrict__ batch,
                        unsigned* __restrict__ x1k, float* __restrict__ x2,
                        float* __restrict__ cnt) {
    int c0 = blockIdx.x * 64;
    if (c0 >= NN) return;
    int o = threadIdx.x;
    int endn = min(c0 + 64, NN);
    int g = batch[c0];
    float mx = -INFINITY, sm = 0.f, cl = 0.f;
    for (int nd = c0; nd < endn; nd++) {
        int bg = batch[nd];
        if (bg != g) {
            atomicMax(&x1k[g * 256 + o], fkey(mx));
            atomicAdd(&x2[g * 256 + o], sm);
            if (o == 0) atomicAdd(&cnt[g], cl);
            g = bg; mx = -INFINITY; sm = 0.f; cl = 0.f;
        }
        float hv = H[(size_t)nd * 256 + o];
        mx = fmaxf(mx, hv);
        sm += hv;
        cl += 1.f;
    }
    atomicMax(&x1k[g * 256 + o], fkey(mx));
    atomicAdd(&x2[g * 256 + o], sm);
    if (o == 0) atomicAdd(&cnt[g], cl);
}

// ================= fused dense tail: one block per graph, split-K layers =================
// T = 256/DOUT threads cooperate per output; 4 independent partials for ILP.
template<int DIN, int DOUT, int ACT>
__device__ __forceinline__ void dense_layer(const float* __restrict__ in,
                                            const float* __restrict__ W,
                                            const float* __restrict__ B,
                                            float* __restrict__ out, int o,
                                            float* __restrict__ red) {
    constexpr int T = 256 / DOUT;
    constexpr int KS = DIN / T;
    int oo = o % DOUT;
    int kk = o / DOUT;
    int kbase = kk * KS;
    float p0 = 0.f, p1 = 0.f, p2 = 0.f, p3 = 0.f;
#pragma unroll 4
    for (int k = 0; k < KS; k += 4) {
        p0 += in[kbase + k]     * W[(size_t)(kbase + k) * DOUT + oo];
        p1 += in[kbase + k + 1] * W[(size_t)(kbase + k + 1) * DOUT + oo];
        p2 += in[kbase + k + 2] * W[(size_t)(kbase + k + 2) * DOUT + oo];
        p3 += in[kbase + k + 3] * W[(size_t)(kbase + k + 3) * DOUT + oo];
    }
    float p = (p0 + p1) + (p2 + p3);
    if constexpr (T > 1) {
        red[o] = p;
        __syncthreads();
        if (o < DOUT) {
#pragma unroll
            for (int tt = 1; tt < T; tt++) p += red[oo + tt * DOUT];
        }
    }
    if (o < DOUT) {
        p += B[oo];
        if constexpr (ACT == 1) p = fmaxf(p, 0.f);
        else if constexpr (ACT == 2) p = 1.f / (1.f + expf(-p));
        out[oo] = p;
    }
    __syncthreads();
}

__global__ void k_tail(const unsigned* __restrict__ x1k, const float* __restrict__ x2,
                       const float* __restrict__ cnt,
                       const float* __restrict__ d1w, const float* __restrict__ d1b,
                       const float* __restrict__ d2w, const float* __restrict__ d2b,
                       const float* __restrict__ d3w, const float* __restrict__ d3b,
                       const float* __restrict__ mw,  const float* __restrict__ mb,
                       const float* __restrict__ d4w, const float* __restrict__ d4b,
                       const float* __restrict__ d5w, const float* __restrict__ d5b,
                       const float* __restrict__ d6w, const float* __restrict__ d6b,
                       const float* __restrict__ d7w, const float* __restrict__ d7b,
                       float* __restrict__ out) {
    __shared__ float z[512];
    __shared__ float A[256];
    __shared__ float Bf[256];
    __shared__ float red[256];
    __shared__ float x3s[256];
    __shared__ float gbuf[64];
    int g = blockIdx.x, o = threadIdx.x;   // 256 threads
    float c = fmaxf(cnt[g], 1.f);
    float sv = x2[(size_t)g * 256 + o];
    z[o] = fkey_inv(x1k[(size_t)g * 256 + o]);
    z[256 + o] = sv;
    x3s[o] = sv / c;
    __syncthreads();
    dense_layer<512, 256, 1>(z,   d1w, d1b, A,    o, red);   // d1 relu
    dense_layer<256, 128, 1>(A,   d2w, d2b, Bf,   o, red);   // d2 relu
    dense_layer<128,  64, 1>(Bf,  d3w, d3b, A,    o, red);   // d3 relu
    dense_layer<256,  64, 2>(x3s, mw,  mb,  gbuf, o, red);   // sigmoid gate
    if (o < 64) A[o] *= gbuf[o];
    __syncthreads();
    dense_layer< 64,  64, 1>(A,   d4w, d4b, Bf,   o, red);   // d4 relu
    dense_layer< 64, 128, 1>(Bf,  d5w, d5b, A,    o, red);   // d5 relu
    dense_layer<128, 256, 1>(A,   d6w, d6b, z,    o, red);   // d6 relu
    dense_layer<256, 128, 0>(z,   d7w, d7b, A,    o, red);   // d7
    if (o < 128) out[(size_t)g * 128 + o] = A[o];
}

// =====================================================================
extern "C" void kernel_launch(void* const* d_in, const int* in_sizes, int n_in,
                              void* d_out, int out_size, void* d_ws, size_t ws_size,
                              hipStream_t stream) {
    const float* x_in  = (const float*)d_in[0];
    const int*   ei    = (const int*)d_in[1];
    const int*   batch = (const int*)d_in[2];
    const int* src = ei;
    const int* dst = ei + NE;

    const float* Wl[3]  = { (const float*)d_in[3], (const float*)d_in[7],  (const float*)d_in[11] };
    const float* asl[3] = { (const float*)d_in[4], (const float*)d_in[8],  (const float*)d_in[12] };
    const float* adl[3] = { (const float*)d_in[5], (const float*)d_in[9],  (const float*)d_in[13] };
    const float* bl[3]  = { (const float*)d_in[6], (const float*)d_in[10], (const float*)d_in[14] };
    const int din[3]  = {128, 64, 128};

    const float* d1w = (const float*)d_in[15]; const float* d1b = (const float*)d_in[16];
    const float* d2w = (const float*)d_in[17]; const float* d2b = (const float*)d_in[18];
    const float* d3w = (const float*)d_in[19]; const float* d3b = (const float*)d_in[20];
    const float* mw  = (const float*)d_in[21]; const float* mb  = (const float*)d_in[22];
    const float* d4w = (const float*)d_in[23]; const float* d4b = (const float*)d_in[24];
    const float* d5w = (const float*)d_in[25]; const float* d5b = (const float*)d_in[26];
    const float* d6w = (const float*)d_in[27]; const float* d6b = (const float*)d_in[28];
    const float* d7w = (const float*)d_in[29]; const float* d7b = (const float*)d_in[30];

    // -------- workspace carve --------
    float* ws = (float*)d_ws;
    size_t off = 0;
    float* Xbuf  = ws + off; off += (size_t)NN * 256;       // layer output / next input (f32)
    unsigned short* Hb = (unsigned short*)(ws + off); off += (size_t)NN * 128;  // bf16 H
    float* sbuf  = ws + off; off += NN;
    float* tbuf  = ws + off; off += NN;
    unsigned* x1k = (unsigned*)(ws + off); off += NG * 256;
    float* x2    = ws + off; off += NG * 256;
    float* cnt   = ws + off; off += NG;
    int* ip      = (int*)(ws + off);
    int* deg     = ip;               ip += NN;
    int* excl    = ip;               ip += NN;
    int* partials= ip;               ip += SCAN_B;
    int* rowptr  = ip;               ip += NN + 1;
    int* cursor  = ip;               ip += NN;
    int* srcsort = ip;               ip += NEP;

    const int nb = (NN + SCAN_B - 1) / SCAN_B;

    // -------- CSR build (reused by all 3 layers) --------
    k_zero_int<<<(NN + 255) / 256, 256, 0, stream>>>(deg, NN);
    k_hist<<<(NEP + 255) / 256, 256, 0, stream>>>(dst, deg);
    k_scan1<<<nb, SCAN_B, 0, stream>>>(deg, excl, partials, NN);
    k_scan2<<<1, SCAN_B, 0, stream>>>(partials, nb);
    k_scan3<<<nb, SCAN_B, 0, stream>>>(excl, partials, rowptr, cursor, NN);
    k_scatter<<<(NEP + 255) / 256, 256, 0, stream>>>(src, dst, cursor, srcsort);

    // -------- three GAT layers --------
    for (int l = 0; l < 3; l++) {
        const float* X = (l == 0) ? x_in : Xbuf;
        dim3 gblk(64, 4);
        dim3 ggrd(1, NN / 16);
        if (l == 0)      k_gemm_t<1><<<ggrd, gblk, 0, stream>>>(X, Wl[l], Hb, asl[l], adl[l], sbuf, tbuf, din[l]);
        else if (l == 1) k_gemm_t<2><<<ggrd, gblk, 0, stream>>>(X, Wl[l], Hb, asl[l], adl[l], sbuf, tbuf, din[l]);
        else             k_gemm_t<4><<<ggrd, gblk, 0, stream>>>(X, Wl[l], Hb, asl[l], adl[l], sbuf, tbuf, din[l]);
        int agrid = (NN + 3) / 4;
        if (l == 0)      k_agg<64><<<agrid, 256, 0, stream>>>(rowptr, srcsort, sbuf, tbuf, Hb, bl[l], Xbuf);
        else if (l == 1) k_agg<128><<<agrid, 256, 0, stream>>>(rowptr, srcsort, sbuf, tbuf, Hb, bl[l], Xbuf);
        else             k_agg<256><<<agrid, 256, 0, stream>>>(rowptr, srcsort, sbuf, tbuf, Hb, bl[l], Xbuf);
    }

    // -------- pooling + fused tail --------
    k_pool_init<<<(NG * 256 + 255) / 256, 256, 0, stream>>>(x1k, x2, cnt);
    k_pool2<<<(NN + 63) / 64, 256, 0, stream>>>(Xbuf, batch, x1k, x2, cnt);
    k_tail<<<NG, 256, 0, stream>>>(x1k, x2, cnt,
                                   d1w, d1b, d2w, d2b, d3w, d3b, mw, mb,
                                   d4w, d4b, d5w, d5b, d6w, d6b, d7w, d7b,
                                   (float*)d_out);
}

// Round 8
// 457.885 us; speedup vs baseline: 5.5710x; 1.1276x over previous
//
#include <hip/hip_runtime.h>
#include <hip/hip_bf16.h>
#include <math.h>

#define NN 50000      // nodes
#define NE 800000     // edges (without self loops)
#define NEP 850000    // edges + self loops
#define NG 64         // graphs
#define SCAN_B 256

typedef unsigned short u16;
typedef __attribute__((ext_vector_type(8))) short short8;    // 8 bf16 (4 VGPRs) MFMA A/B frag
typedef __attribute__((ext_vector_type(4))) float f32x4;     // MFMA C/D frag

__device__ __forceinline__ float bfu2f(u16 u) {
    return __uint_as_float((unsigned)u << 16);
}
__device__ __forceinline__ u16 f2bfu(float f) {
    __hip_bfloat16 h = __float2bfloat16(f);   // RTNE
    union { __hip_bfloat16 h; u16 u; } c; c.h = h; return c.u;
}

// order-preserving float -> uint key
__device__ __forceinline__ unsigned fkey(float f) {
    unsigned u = __float_as_uint(f);
    return (u & 0x80000000u) ? ~u : (u | 0x80000000u);
}
__device__ __forceinline__ float fkey_inv(unsigned k) {
    return (k & 0x80000000u) ? __uint_as_float(k ^ 0x80000000u) : __uint_as_float(~k);
}

// ================= CSR build =================
__global__ void k_zero_int(int* __restrict__ p, int n) {
    int i = blockIdx.x * blockDim.x + threadIdx.x;
    if (i < n) p[i] = 0;
}

__global__ void k_hist(const int* __restrict__ dst, int* __restrict__ deg) {
    int i = blockIdx.x * blockDim.x + threadIdx.x;
    if (i >= NEP) return;
    int dv = (i < NE) ? dst[i] : (i - NE);
    atomicAdd(&deg[dv], 1);
}

__global__ void k_scan1(const int* __restrict__ deg, int* __restrict__ excl,
                        int* __restrict__ partials, int n) {
    __shared__ int sh[SCAN_B];
    int i = blockIdx.x * SCAN_B + threadIdx.x;
    int v = (i < n) ? deg[i] : 0;
    sh[threadIdx.x] = v;
    __syncthreads();
    for (int off = 1; off < SCAN_B; off <<= 1) {
        int t = (threadIdx.x >= off) ? sh[threadIdx.x - off] : 0;
        __syncthreads();
        sh[threadIdx.x] += t;
        __syncthreads();
    }
    if (i < n) excl[i] = sh[threadIdx.x] - v;
    if (threadIdx.x == SCAN_B - 1) partials[blockIdx.x] = sh[threadIdx.x];
}

__global__ void k_scan2(int* __restrict__ partials, int nb) {  // single block
    __shared__ int sh[SCAN_B];
    int v = (threadIdx.x < nb) ? partials[threadIdx.x] : 0;
    sh[threadIdx.x] = v;
    __syncthreads();
    for (int off = 1; off < SCAN_B; off <<= 1) {
        int t = (threadIdx.x >= off) ? sh[threadIdx.x - off] : 0;
        __syncthreads();
        sh[threadIdx.x] += t;
        __syncthreads();
    }
    if (threadIdx.x < nb) partials[threadIdx.x] = sh[threadIdx.x] - v;
}

__global__ void k_scan3(const int* __restrict__ excl, const int* __restrict__ partials,
                        int* __restrict__ rowptr, int* __restrict__ cursor, int n) {
    int i = blockIdx.x * SCAN_B + threadIdx.x;
    if (i < n) {
        int r = excl[i] + partials[blockIdx.x];
        rowptr[i] = r;
        cursor[i] = r;
    }
    if (i == 0) rowptr[n] = NEP;
}

__global__ void k_scatter(const int* __restrict__ src, const int* __restrict__ dst,
                          int* __restrict__ cursor, int* __restrict__ srcsort) {
    int i = blockIdx.x * blockDim.x + threadIdx.x;
    if (i >= NEP) return;
    int sv = (i < NE) ? src[i] : (i - NE);
    int dv = (i < NE) ? dst[i] : (i - NE);
    int pos = atomicAdd(&cursor[dv], 1);
    srcsort[pos] = sv;
}

// ================= layer prep: Wb = bf16(W); wa = W.asv, wb = W.adv =================
// grid = din blocks; block 256.
__global__ void k_prep(const float* __restrict__ W, const float* __restrict__ asv,
                       const float* __restrict__ adv, u16* __restrict__ Wb,
                       float* __restrict__ wa, float* __restrict__ wb, int dout) {
    __shared__ float pas[4], pbs[4];
    int k = blockIdx.x, tid = threadIdx.x;
    float pa = 0.f, pb = 0.f;
    for (int n = tid; n < dout; n += 256) {
        float w = W[(size_t)k * dout + n];
        Wb[(size_t)k * dout + n] = f2bfu(w);
        pa += w * asv[n];
        pb += w * adv[n];
    }
#pragma unroll
    for (int off = 32; off; off >>= 1) {
        pa += __shfl_xor(pa, off);
        pb += __shfl_xor(pb, off);
    }
    if ((tid & 63) == 0) { pas[tid >> 6] = pa; pbs[tid >> 6] = pb; }
    __syncthreads();
    if (tid == 0) {
        wa[k] = pas[0] + pas[1] + pas[2] + pas[3];
        wb[k] = pbs[0] + pbs[1] + pbs[2] + pbs[3];
    }
}

// ================= s,t = X . wa, X . wb  (wave per node) =================
template<int DIN, bool XF32>
__global__ void k_st(const void* __restrict__ Xin, const float* __restrict__ wa,
                     const float* __restrict__ wb, float* __restrict__ s,
                     float* __restrict__ t) {
    int node = blockIdx.x * 4 + (threadIdx.x >> 6);
    int lane = threadIdx.x & 63;
    float pa = 0.f, pb = 0.f;
    if constexpr (DIN == 128) {
        float x0, x1;
        if constexpr (XF32) {
            const float* p = (const float*)Xin + (size_t)node * 128 + lane * 2;
            x0 = p[0]; x1 = p[1];
        } else {
            unsigned u = *(const unsigned*)((const u16*)Xin + (size_t)node * 128 + lane * 2);
            x0 = bfu2f((u16)(u & 0xffff)); x1 = bfu2f((u16)(u >> 16));
        }
        pa = x0 * wa[lane * 2] + x1 * wa[lane * 2 + 1];
        pb = x0 * wb[lane * 2] + x1 * wb[lane * 2 + 1];
    } else {   // 64, bf16
        float x0 = bfu2f(((const u16*)Xin)[(size_t)node * 64 + lane]);
        pa = x0 * wa[lane]; pb = x0 * wb[lane];
    }
#pragma unroll
    for (int off = 32; off; off >>= 1) {
        pa += __shfl_xor(pa, off);
        pb += __shfl_xor(pb, off);
    }
    if (lane == 0) { s[node] = pa; t[node] = pb; }
}

// ================= MFMA GEMM: Hb[NN,DOUT](bf16) = X[NN,DIN] @ Wb[DIN,DOUT] =================
// 64 rows/block, 4 waves split columns. W fragments live in registers (loaded once).
// mfma_f32_16x16x32_bf16 layouts (HW-verified): A[m=lane&15][k=(lane>>4)*8+j],
// B[n=lane&15][k=(lane>>4)*8+j], C col=lane&15, row=(lane>>4)*4+reg.
template<int DIN, int DOUT, bool XF32>
__global__ __launch_bounds__(256) void k_gemm_mfma(const void* __restrict__ Xin,
                                                   const u16* __restrict__ Wb,
                                                   u16* __restrict__ Hb) {
    constexpr int KS = DIN / 32;        // K steps per mfma chain
    constexpr int CT = DOUT / 16;       // 16-col tiles
    constexpr int TPW = CT / 4;         // col tiles per wave
    constexpr int STRIDE = DIN + 16;    // LDS row stride (bf16 elems): 16B-aligned, conflict-padded
    __shared__ u16 Xs[64 * STRIDE];
    int tid = threadIdx.x, wave = tid >> 6, lane = tid & 63;
    int quad = lane >> 4, l15 = lane & 15;
    int n0 = blockIdx.x * 64;

    // ---- B fragments -> registers (once) ----
    short8 bfr[TPW][KS];
#pragma unroll
    for (int ct = 0; ct < TPW; ct++) {
        int nb = (wave * TPW + ct) * 16 + l15;
#pragma unroll
        for (int ks = 0; ks < KS; ks++) {
            int kb = ks * 32 + quad * 8;
            short8 b;
#pragma unroll
            for (int j = 0; j < 8; j++) b[j] = (short)Wb[(size_t)(kb + j) * DOUT + nb];
            bfr[ct][ks] = b;
        }
    }

    // ---- stage X (64 rows) to LDS as bf16 ----
    for (int c = tid; c < 64 * DIN / 8; c += 256) {
        int row = (c * 8) / DIN, col = (c * 8) % DIN;
        int rg = n0 + row; if (rg >= NN) rg = NN - 1;
        u16 v[8];
        if constexpr (XF32) {
            const float* p = (const float*)Xin + (size_t)rg * DIN + col;
            float4 f0 = *(const float4*)p;
            float4 f1 = *(const float4*)(p + 4);
            v[0] = f2bfu(f0.x); v[1] = f2bfu(f0.y); v[2] = f2bfu(f0.z); v[3] = f2bfu(f0.w);
            v[4] = f2bfu(f1.x); v[5] = f2bfu(f1.y); v[6] = f2bfu(f1.z); v[7] = f2bfu(f1.w);
        } else {
            const u16* p = (const u16*)Xin + (size_t)rg * DIN + col;
            ushort4 a = *(const ushort4*)p;
            ushort4 b = *(const ushort4*)(p + 4);
            v[0] = a.x; v[1] = a.y; v[2] = a.z; v[3] = a.w;
            v[4] = b.x; v[5] = b.y; v[6] = b.z; v[7] = b.w;
        }
        u16* d = &Xs[row * STRIDE + col];
#pragma unroll
        for (int j = 0; j < 8; j++) d[j] = v[j];
    }
    __syncthreads();

    // ---- 4 row-tiles of 16 ----
#pragma unroll
    for (int rt = 0; rt < 4; rt++) {
        short8 afr[KS];
#pragma unroll
        for (int ks = 0; ks < KS; ks++)
            afr[ks] = *(const short8*)&Xs[(rt * 16 + l15) * STRIDE + ks * 32 + quad * 8];
#pragma unroll
        for (int ct = 0; ct < TPW; ct++) {
            f32x4 cf = {0.f, 0.f, 0.f, 0.f};
#pragma unroll
            for (int ks = 0; ks < KS; ks++)
                cf = __builtin_amdgcn_mfma_f32_16x16x32_bf16(afr[ks], bfr[ct][ks], cf, 0, 0, 0);
            int col = (wave * TPW + ct) * 16 + l15;
            int rbase = n0 + rt * 16 + quad * 4;
#pragma unroll
            for (int reg = 0; reg < 4; reg++) {
                int r = rbase + reg;
                if (r < NN) Hb[(size_t)r * DOUT + col] = f2bfu(cf[reg]);
            }
        }
    }
}

// ================= fused softmax + aggregation: wave per dst node =================
template<int DOUT, bool OBF>
__global__ void k_agg(const int* __restrict__ rowptr, const int* __restrict__ srcsort,
                      const float* __restrict__ s, const float* __restrict__ t,
                      const u16* __restrict__ Hb, const float* __restrict__ bias,
                      void* __restrict__ OUT) {
    constexpr int R = DOUT / 64;
    int node = blockIdx.x * 4 + (threadIdx.x >> 6);
    int lane = threadIdx.x & 63;
    if (node >= NN) return;
    int beg = rowptr[node], end = rowptr[node + 1];
    float tn = t[node];
    int j0 = beg + lane;
    float ex0 = 0.f; int sv0 = 0;
    if (j0 < end) {
        sv0 = srcsort[j0];
        float e = s[sv0] + tn;
        e = (e > 0.f) ? e : 0.2f * e;
        ex0 = expf(e);
    }
    float dsum = ex0;
    for (int j = j0 + 64; j < end; j += 64) {
        float e = s[srcsort[j]] + tn;
        e = (e > 0.f) ? e : 0.2f * e;
        dsum += expf(e);
    }
#pragma unroll
    for (int off = 32; off; off >>= 1) dsum += __shfl_xor(dsum, off);
    float inv = 1.f / dsum;   // self-loop guarantees dsum > 0
    float acc[R];
#pragma unroll
    for (int o = 0; o < R; o++) acc[o] = bias[lane * R + o];

    auto gather = [&](float exv, int svv, int cnt) {
        int q = 0;
        for (; q + 4 <= cnt; q += 4) {
            float a0 = __shfl(exv, q),     a1 = __shfl(exv, q + 1);
            float a2 = __shfl(exv, q + 2), a3 = __shfl(exv, q + 3);
            int i0 = __shfl(svv, q),     i1 = __shfl(svv, q + 1);
            int i2 = __shfl(svv, q + 2), i3 = __shfl(svv, q + 3);
            if constexpr (R == 4) {
                ushort4 u0 = *(const ushort4*)(Hb + (size_t)i0 * DOUT + lane * 4);
                ushort4 u1 = *(const ushort4*)(Hb + (size_t)i1 * DOUT + lane * 4);
                ushort4 u2 = *(const ushort4*)(Hb + (size_t)i2 * DOUT + lane * 4);
                ushort4 u3 = *(const ushort4*)(Hb + (size_t)i3 * DOUT + lane * 4);
                acc[0] += a0 * bfu2f(u0.x); acc[1] += a0 * bfu2f(u0.y);
                acc[2] += a0 * bfu2f(u0.z); acc[3] += a0 * bfu2f(u0.w);
                acc[0] += a1 * bfu2f(u1.x); acc[1] += a1 * bfu2f(u1.y);
                acc[2] += a1 * bfu2f(u1.z); acc[3] += a1 * bfu2f(u1.w);
                acc[0] += a2 * bfu2f(u2.x); acc[1] += a2 * bfu2f(u2.y);
                acc[2] += a2 * bfu2f(u2.z); acc[3] += a2 * bfu2f(u2.w);
                acc[0] += a3 * bfu2f(u3.x); acc[1] += a3 * bfu2f(u3.y);
                acc[2] += a3 * bfu2f(u3.z); acc[3] += a3 * bfu2f(u3.w);
            } else if constexpr (R == 2) {
                ushort2 u0 = *(const ushort2*)(Hb + (size_t)i0 * DOUT + lane * 2);
                ushort2 u1 = *(const ushort2*)(Hb + (size_t)i1 * DOUT + lane * 2);
                ushort2 u2 = *(const ushort2*)(Hb + (size_t)i2 * DOUT + lane * 2);
                ushort2 u3 = *(const ushort2*)(Hb + (size_t)i3 * DOUT + lane * 2);
                acc[0] += a0 * bfu2f(u0.x); acc[1] += a0 * bfu2f(u0.y);
                acc[0] += a1 * bfu2f(u1.x); acc[1] += a1 * bfu2f(u1.y);
                acc[0] += a2 * bfu2f(u2.x); acc[1] += a2 * bfu2f(u2.y);
                acc[0] += a3 * bfu2f(u3.x); acc[1] += a3 * bfu2f(u3.y);
            } else {
                u16 u0 = Hb[(size_t)i0 * DOUT + lane];
                u16 u1 = Hb[(size_t)i1 * DOUT + lane];
                u16 u2 = Hb[(size_t)i2 * DOUT + lane];
                u16 u3 = Hb[(size_t)i3 * DOUT + lane];
                acc[0] += a0 * bfu2f(u0) + a1 * bfu2f(u1) + a2 * bfu2f(u2) + a3 * bfu2f(u3);
            }
        }
        for (; q < cnt; q++) {
            float a = __shfl(exv, q);
            int  i = __shfl(svv, q);
            const u16* hrow = Hb + (size_t)i * DOUT + lane * R;
            if constexpr (R == 4) {
                ushort4 u = *(const ushort4*)hrow;
                acc[0] += a * bfu2f(u.x); acc[1] += a * bfu2f(u.y);
                acc[2] += a * bfu2f(u.z); acc[3] += a * bfu2f(u.w);
            } else if constexpr (R == 2) {
                ushort2 u = *(const ushort2*)hrow;
                acc[0] += a * bfu2f(u.x); acc[1] += a * bfu2f(u.y);
            } else {
                acc[0] += a * bfu2f(hrow[0]);
            }
        }
    };

    gather(ex0 * inv, sv0, min(64, end - beg));
    for (int cbeg = beg + 64; cbeg < end; cbeg += 64) {
        int j = cbeg + lane;
        float ex = 0.f; int sv = 0;
        if (j < end) {
            sv = srcsort[j];
            float e = s[sv] + tn;
            e = (e > 0.f) ? e : 0.2f * e;
            ex = expf(e) * inv;
        }
        gather(ex, sv, min(64, end - cbeg));
    }

    if constexpr (OBF) {
        u16* orow = (u16*)OUT + (size_t)node * DOUT + lane * R;
        if constexpr (R == 2) {
            union { ushort2 u2; unsigned u; } p;
            p.u2.x = f2bfu(acc[0]); p.u2.y = f2bfu(acc[1]);
            *(unsigned*)orow = p.u;
        } else {
            orow[0] = f2bfu(acc[0]);
        }
    } else {
        float* orow = (float*)OUT + (size_t)node * DOUT + lane * R;
        *(float4*)orow = make_float4(acc[0], acc[1], acc[2], acc[3]);
    }
}

// ================= pooling =================
__global__ void k_pool_init(unsigned* __restrict__ x1k, float* __restrict__ x2, float* __restrict__ cnt) {
    int i = blockIdx.x * blockDim.x + threadIdx.x;
    if (i < NG * 256) { x1k[i] = 0u; x2[i] = 0.f; }
    if (i < NG) cnt[i] = 0.f;
}

__global__ void k_pool2(const float* __restrict__ H, const int* __restrict__ batch,
                        unsigned* __restrict__ x1k, float* __restrict__ x2,
                        float* __restrict__ cnt) {
    int c0 = blockIdx.x * 64;
    if (c0 >= NN) return;
    int o = threadIdx.x;
    int endn = min(c0 + 64, NN);
    int g = batch[c0];
    float mx = -INFINITY, sm = 0.f, cl = 0.f;
    for (int nd = c0; nd < endn; nd++) {
        int bg = batch[nd];
        if (bg != g) {
            atomicMax(&x1k[g * 256 + o], fkey(mx));
            atomicAdd(&x2[g * 256 + o], sm);
            if (o == 0) atomicAdd(&cnt[g], cl);
            g = bg; mx = -INFINITY; sm = 0.f; cl = 0.f;
        }
        float hv = H[(size_t)nd * 256 + o];
        mx = fmaxf(mx, hv);
        sm += hv;
        cl += 1.f;
    }
    atomicMax(&x1k[g * 256 + o], fkey(mx));
    atomicAdd(&x2[g * 256 + o], sm);
    if (o == 0) atomicAdd(&cnt[g], cl);
}

// ================= fused dense tail =================
template<int DIN, int DOUT, int ACT>
__device__ __forceinline__ void dense_layer(const float* __restrict__ in,
                                            const float* __restrict__ W,
                                            const float* __restrict__ B,
                                            float* __restrict__ out, int o,
                                            float* __restrict__ red) {
    constexpr int T = 256 / DOUT;
    constexpr int KS = DIN / T;
    int oo = o % DOUT;
    int kk = o / DOUT;
    int kbase = kk * KS;
    float p0 = 0.f, p1 = 0.f, p2 = 0.f, p3 = 0.f;
#pragma unroll 4
    for (int k = 0; k < KS; k += 4) {
        p0 += in[kbase + k]     * W[(size_t)(kbase + k) * DOUT + oo];
        p1 += in[kbase + k + 1] * W[(size_t)(kbase + k + 1) * DOUT + oo];
        p2 += in[kbase + k + 2] * W[(size_t)(kbase + k + 2) * DOUT + oo];
        p3 += in[kbase + k + 3] * W[(size_t)(kbase + k + 3) * DOUT + oo];
    }
    float p = (p0 + p1) + (p2 + p3);
    if constexpr (T > 1) {
        red[o] = p;
        __syncthreads();
        if (o < DOUT) {
#pragma unroll
            for (int tt = 1; tt < T; tt++) p += red[oo + tt * DOUT];
        }
    }
    if (o < DOUT) {
        p += B[oo];
        if constexpr (ACT == 1) p = fmaxf(p, 0.f);
        else if constexpr (ACT == 2) p = 1.f / (1.f + expf(-p));
        out[oo] = p;
    }
    __syncthreads();
}

__global__ void k_tail(const unsigned* __restrict__ x1k, const float* __restrict__ x2,
                       const float* __restrict__ cnt,
                       const float* __restrict__ d1w, const float* __restrict__ d1b,
                       const float* __restrict__ d2w, const float* __restrict__ d2b,
                       const float* __restrict__ d3w, const float* __restrict__ d3b,
                       const float* __restrict__ mw,  const float* __restrict__ mb,
                       const float* __restrict__ d4w, const float* __restrict__ d4b,
                       const float* __restrict__ d5w, const float* __restrict__ d5b,
                       const float* __restrict__ d6w, const float* __restrict__ d6b,
                       const float* __restrict__ d7w, const float* __restrict__ d7b,
                       float* __restrict__ out) {
    __shared__ float z[512];
    __shared__ float A[256];
    __shared__ float Bf[256];
    __shared__ float red[256];
    __shared__ float x3s[256];
    __shared__ float gbuf[64];
    int g = blockIdx.x, o = threadIdx.x;
    float c = fmaxf(cnt[g], 1.f);
    float sv = x2[(size_t)g * 256 + o];
    z[o] = fkey_inv(x1k[(size_t)g * 256 + o]);
    z[256 + o] = sv;
    x3s[o] = sv / c;
    __syncthreads();
    dense_layer<512, 256, 1>(z,   d1w, d1b, A,    o, red);
    dense_layer<256, 128, 1>(A,   d2w, d2b, Bf,   o, red);
    dense_layer<128,  64, 1>(Bf,  d3w, d3b, A,    o, red);
    dense_layer<256,  64, 2>(x3s, mw,  mb,  gbuf, o, red);
    if (o < 64) A[o] *= gbuf[o];
    __syncthreads();
    dense_layer< 64,  64, 1>(A,   d4w, d4b, Bf,   o, red);
    dense_layer< 64, 128, 1>(Bf,  d5w, d5b, A,    o, red);
    dense_layer<128, 256, 1>(A,   d6w, d6b, z,    o, red);
    dense_layer<256, 128, 0>(z,   d7w, d7b, A,    o, red);
    if (o < 128) out[(size_t)g * 128 + o] = A[o];
}

// =====================================================================
extern "C" void kernel_launch(void* const* d_in, const int* in_sizes, int n_in,
                              void* d_out, int out_size, void* d_ws, size_t ws_size,
                              hipStream_t stream) {
    const float* x_in  = (const float*)d_in[0];
    const int*   ei    = (const int*)d_in[1];
    const int*   batch = (const int*)d_in[2];
    const int* src = ei;
    const int* dst = ei + NE;

    const float* Wl[3]  = { (const float*)d_in[3], (const float*)d_in[7],  (const float*)d_in[11] };
    const float* asl[3] = { (const float*)d_in[4], (const float*)d_in[8],  (const float*)d_in[12] };
    const float* adl[3] = { (const float*)d_in[5], (const float*)d_in[9],  (const float*)d_in[13] };
    const float* bl[3]  = { (const float*)d_in[6], (const float*)d_in[10], (const float*)d_in[14] };

    const float* d1w = (const float*)d_in[15]; const float* d1b = (const float*)d_in[16];
    const float* d2w = (const float*)d_in[17]; const float* d2b = (const float*)d_in[18];
    const float* d3w = (const float*)d_in[19]; const float* d3b = (const float*)d_in[20];
    const float* mw  = (const float*)d_in[21]; const float* mb  = (const float*)d_in[22];
    const float* d4w = (const float*)d_in[23]; const float* d4b = (const float*)d_in[24];
    const float* d5w = (const float*)d_in[25]; const float* d5b = (const float*)d_in[26];
    const float* d6w = (const float*)d_in[27]; const float* d6b = (const float*)d_in[28];
    const float* d7w = (const float*)d_in[29]; const float* d7b = (const float*)d_in[30];

    // -------- workspace carve --------
    float* ws = (float*)d_ws;
    size_t off = 0;
    float* Xbuf  = ws + off; off += (size_t)NN * 256;                   // layer-3 agg out (f32, pooling input)
    u16* Hb = (u16*)(ws + off); off += (size_t)NN * 128;                // bf16 H [NN][<=256]
    u16* Xb = (u16*)(ws + off); off += (size_t)NN * 64;                 // bf16 activations [NN][<=128]
    float* sbuf  = ws + off; off += NN;
    float* tbuf  = ws + off; off += NN;
    u16* Wb0 = (u16*)(ws + off); off += (128 * 64) / 2;
    u16* Wb1 = (u16*)(ws + off); off += (64 * 128) / 2;
    u16* Wb2 = (u16*)(ws + off); off += (128 * 256) / 2;
    float* wa0 = ws + off; off += 128;  float* wb0 = ws + off; off += 128;
    float* wa1 = ws + off; off += 64;   float* wb1 = ws + off; off += 64;
    float* wa2 = ws + off; off += 128;  float* wb2 = ws + off; off += 128;
    unsigned* x1k = (unsigned*)(ws + off); off += NG * 256;
    float* x2    = ws + off; off += NG * 256;
    float* cnt   = ws + off; off += NG;
    int* ip      = (int*)(ws + off);
    int* deg     = ip;               ip += NN;
    int* excl    = ip;               ip += NN;
    int* partials= ip;               ip += SCAN_B;
    int* rowptr  = ip;               ip += NN + 1;
    int* cursor  = ip;               ip += NN;
    int* srcsort = ip;               ip += NEP;

    const int nb = (NN + SCAN_B - 1) / SCAN_B;
    const int GB = (NN + 63) / 64;      // 782 gemm blocks
    const int AB = (NN + 3) / 4;        // agg/st blocks

    // -------- CSR build --------
    k_zero_int<<<(NN + 255) / 256, 256, 0, stream>>>(deg, NN);
    k_hist<<<(NEP + 255) / 256, 256, 0, stream>>>(dst, deg);
    k_scan1<<<nb, SCAN_B, 0, stream>>>(deg, excl, partials, NN);
    k_scan2<<<1, SCAN_B, 0, stream>>>(partials, nb);
    k_scan3<<<nb, SCAN_B, 0, stream>>>(excl, partials, rowptr, cursor, NN);
    k_scatter<<<(NEP + 255) / 256, 256, 0, stream>>>(src, dst, cursor, srcsort);

    // -------- per-layer weight prep --------
    k_prep<<<128, 256, 0, stream>>>(Wl[0], asl[0], adl[0], Wb0, wa0, wb0, 64);
    k_prep<<<64,  256, 0, stream>>>(Wl[1], asl[1], adl[1], Wb1, wa1, wb1, 128);
    k_prep<<<128, 256, 0, stream>>>(Wl[2], asl[2], adl[2], Wb2, wa2, wb2, 256);

    // -------- layer 1: x_in(f32,128) -> Hb(64) -> Xb(bf16,64) --------
    k_st<128, true><<<AB, 256, 0, stream>>>(x_in, wa0, wb0, sbuf, tbuf);
    k_gemm_mfma<128, 64, true><<<GB, 256, 0, stream>>>(x_in, Wb0, Hb);
    k_agg<64, true><<<AB, 256, 0, stream>>>(rowptr, srcsort, sbuf, tbuf, Hb, bl[0], Xb);

    // -------- layer 2: Xb(64) -> Hb(128) -> Xb(bf16,128) --------
    k_st<64, false><<<AB, 256, 0, stream>>>(Xb, wa1, wb1, sbuf, tbuf);
    k_gemm_mfma<64, 128, false><<<GB, 256, 0, stream>>>(Xb, Wb1, Hb);
    k_agg<128, true><<<AB, 256, 0, stream>>>(rowptr, srcsort, sbuf, tbuf, Hb, bl[1], Xb);

    // -------- layer 3: Xb(128) -> Hb(256) -> Xbuf(f32,256) --------
    k_st<128, false><<<AB, 256, 0, stream>>>(Xb, wa2, wb2, sbuf, tbuf);
    k_gemm_mfma<128, 256, false><<<GB, 256, 0, stream>>>(Xb, Wb2, Hb);
    k_agg<256, false><<<AB, 256, 0, stream>>>(rowptr, srcsort, sbuf, tbuf, Hb, bl[2], Xbuf);

    // -------- pooling + fused tail --------
    k_pool_init<<<(NG * 256 + 255) / 256, 256, 0, stream>>>(x1k, x2, cnt);
    k_pool2<<<(NN + 63) / 64, 256, 0, stream>>>(Xbuf, batch, x1k, x2, cnt);
    k_tail<<<NG, 256, 0, stream>>>(x1k, x2, cnt,
                                   d1w, d1b, d2w, d2b, d3w, d3b, mw, mb,
                                   d4w, d4b, d5w, d5b, d6w, d6b, d7w, d7b,
                                   (float*)d_out);
}

// Round 9
// 456.122 us; speedup vs baseline: 5.5925x; 1.0039x over previous
//
#include <hip/hip_runtime.h>
#include <hip/hip_bf16.h>
#include <math.h>

#define NN 50000      // nodes
#define NE 800000     // edges (without self loops)
#define NEP 850000    // edges + self loops
#define NG 64         // graphs
#define SCAN_B 256

typedef unsigned short u16;
typedef __attribute__((ext_vector_type(8))) short short8;    // 8 bf16 (4 VGPRs) MFMA A/B frag
typedef __attribute__((ext_vector_type(4))) float f32x4;     // MFMA C/D frag

__device__ __forceinline__ float bfu2f(u16 u) {
    return __uint_as_float((unsigned)u << 16);
}
__device__ __forceinline__ u16 f2bfu(float f) {
    __hip_bfloat16 h = __float2bfloat16(f);   // RTNE
    union { __hip_bfloat16 h; u16 u; } c; c.h = h; return c.u;
}

// order-preserving float -> uint key
__device__ __forceinline__ unsigned fkey(float f) {
    unsigned u = __float_as_uint(f);
    return (u & 0x80000000u) ? ~u : (u | 0x80000000u);
}
__device__ __forceinline__ float fkey_inv(unsigned k) {
    return (k & 0x80000000u) ? __uint_as_float(k ^ 0x80000000u) : __uint_as_float(~k);
}

// ================= init: zero two int regions in one launch =================
__global__ void k_zero2(int* __restrict__ a, int na, int* __restrict__ b, int nb) {
    int i = blockIdx.x * blockDim.x + threadIdx.x;
    if (i < na) a[i] = 0;
    else if (i - na < nb) b[i - na] = 0;
}

// ================= CSR build =================
__global__ void k_hist(const int* __restrict__ dst, int* __restrict__ deg) {
    int i = blockIdx.x * blockDim.x + threadIdx.x;
    if (i >= NEP) return;
    int dv = (i < NE) ? dst[i] : (i - NE);
    atomicAdd(&deg[dv], 1);
}

__global__ void k_scan1(const int* __restrict__ deg, int* __restrict__ excl,
                        int* __restrict__ partials, int n) {
    __shared__ int sh[SCAN_B];
    int i = blockIdx.x * SCAN_B + threadIdx.x;
    int v = (i < n) ? deg[i] : 0;
    sh[threadIdx.x] = v;
    __syncthreads();
    for (int off = 1; off < SCAN_B; off <<= 1) {
        int t = (threadIdx.x >= off) ? sh[threadIdx.x - off] : 0;
        __syncthreads();
        sh[threadIdx.x] += t;
        __syncthreads();
    }
    if (i < n) excl[i] = sh[threadIdx.x] - v;
    if (threadIdx.x == SCAN_B - 1) partials[blockIdx.x] = sh[threadIdx.x];
}

__global__ void k_scan2(int* __restrict__ partials, int nb) {  // single block
    __shared__ int sh[SCAN_B];
    int v = (threadIdx.x < nb) ? partials[threadIdx.x] : 0;
    sh[threadIdx.x] = v;
    __syncthreads();
    for (int off = 1; off < SCAN_B; off <<= 1) {
        int t = (threadIdx.x >= off) ? sh[threadIdx.x - off] : 0;
        __syncthreads();
        sh[threadIdx.x] += t;
        __syncthreads();
    }
    if (threadIdx.x < nb) partials[threadIdx.x] = sh[threadIdx.x] - v;
}

__global__ void k_scan3(const int* __restrict__ excl, const int* __restrict__ partials,
                        int* __restrict__ rowptr, int* __restrict__ cursor, int n) {
    int i = blockIdx.x * SCAN_B + threadIdx.x;
    if (i < n) {
        int r = excl[i] + partials[blockIdx.x];
        rowptr[i] = r;
        cursor[i] = r;
    }
    if (i == 0) rowptr[n] = NEP;
}

__global__ void k_scatter(const int* __restrict__ src, const int* __restrict__ dst,
                          int* __restrict__ cursor, int* __restrict__ srcsort) {
    int i = blockIdx.x * blockDim.x + threadIdx.x;
    if (i >= NEP) return;
    int sv = (i < NE) ? src[i] : (i - NE);
    int dv = (i < NE) ? dst[i] : (i - NE);
    int pos = atomicAdd(&cursor[dv], 1);
    srcsort[pos] = sv;
}

// ================= merged layer prep: Wb = bf16(W); wa = W.asv, wb = W.adv =================
// grid = 128+64+128 = 320 blocks
__global__ void k_prep3(const float* __restrict__ W0, const float* __restrict__ as0, const float* __restrict__ ad0,
                        u16* __restrict__ Wb0, float* __restrict__ wa0, float* __restrict__ wb0,
                        const float* __restrict__ W1, const float* __restrict__ as1, const float* __restrict__ ad1,
                        u16* __restrict__ Wb1, float* __restrict__ wa1, float* __restrict__ wb1,
                        const float* __restrict__ W2, const float* __restrict__ as2, const float* __restrict__ ad2,
                        u16* __restrict__ Wb2, float* __restrict__ wa2, float* __restrict__ wb2) {
    __shared__ float pas[4], pbs[4];
    int b = blockIdx.x, tid = threadIdx.x;
    const float *W, *asv, *adv; u16* Wb; float *wa, *wb; int k, dout;
    if (b < 128)      { W = W0; asv = as0; adv = ad0; Wb = Wb0; wa = wa0; wb = wb0; k = b;       dout = 64;  }
    else if (b < 192) { W = W1; asv = as1; adv = ad1; Wb = Wb1; wa = wa1; wb = wb1; k = b - 128; dout = 128; }
    else              { W = W2; asv = as2; adv = ad2; Wb = Wb2; wa = wa2; wb = wb2; k = b - 192; dout = 256; }
    float pa = 0.f, pb = 0.f;
    for (int n = tid; n < dout; n += 256) {
        float w = W[(size_t)k * dout + n];
        Wb[(size_t)k * dout + n] = f2bfu(w);
        pa += w * asv[n];
        pb += w * adv[n];
    }
#pragma unroll
    for (int off = 32; off; off >>= 1) {
        pa += __shfl_xor(pa, off);
        pb += __shfl_xor(pb, off);
    }
    if ((tid & 63) == 0) { pas[tid >> 6] = pa; pbs[tid >> 6] = pb; }
    __syncthreads();
    if (tid == 0) {
        wa[k] = pas[0] + pas[1] + pas[2] + pas[3];
        wb[k] = pbs[0] + pbs[1] + pbs[2] + pbs[3];
    }
}

// ================= s,t = X . wa, X . wb  (layer 1 only; wave per node) =================
__global__ void k_st128(const float* __restrict__ Xin, const float* __restrict__ wa,
                        const float* __restrict__ wb, float* __restrict__ s,
                        float* __restrict__ t) {
    int node = blockIdx.x * 4 + (threadIdx.x >> 6);
    int lane = threadIdx.x & 63;
    const float* p = Xin + (size_t)node * 128 + lane * 2;
    float x0 = p[0], x1 = p[1];
    float pa = x0 * wa[lane * 2] + x1 * wa[lane * 2 + 1];
    float pb = x0 * wb[lane * 2] + x1 * wb[lane * 2 + 1];
#pragma unroll
    for (int off = 32; off; off >>= 1) {
        pa += __shfl_xor(pa, off);
        pb += __shfl_xor(pb, off);
    }
    if (lane == 0) { s[node] = pa; t[node] = pb; }
}

// ================= MFMA GEMM: Hb[NN,DOUT](bf16) = X[NN,DIN] @ Wb[DIN,DOUT] =================
template<int DIN, int DOUT, bool XF32>
__global__ __launch_bounds__(256) void k_gemm_mfma(const void* __restrict__ Xin,
                                                   const u16* __restrict__ Wb,
                                                   u16* __restrict__ Hb) {
    constexpr int KS = DIN / 32;
    constexpr int CT = DOUT / 16;
    constexpr int TPW = CT / 4;
    constexpr int STRIDE = DIN + 16;
    __shared__ u16 Xs[64 * STRIDE];
    int tid = threadIdx.x, wave = tid >> 6, lane = tid & 63;
    int quad = lane >> 4, l15 = lane & 15;
    int n0 = blockIdx.x * 64;

    short8 bfr[TPW][KS];
#pragma unroll
    for (int ct = 0; ct < TPW; ct++) {
        int nb = (wave * TPW + ct) * 16 + l15;
#pragma unroll
        for (int ks = 0; ks < KS; ks++) {
            int kb = ks * 32 + quad * 8;
            short8 b;
#pragma unroll
            for (int j = 0; j < 8; j++) b[j] = (short)Wb[(size_t)(kb + j) * DOUT + nb];
            bfr[ct][ks] = b;
        }
    }

    for (int c = tid; c < 64 * DIN / 8; c += 256) {
        int row = (c * 8) / DIN, col = (c * 8) % DIN;
        int rg = n0 + row; if (rg >= NN) rg = NN - 1;
        u16 v[8];
        if constexpr (XF32) {
            const float* p = (const float*)Xin + (size_t)rg * DIN + col;
            float4 f0 = *(const float4*)p;
            float4 f1 = *(const float4*)(p + 4);
            v[0] = f2bfu(f0.x); v[1] = f2bfu(f0.y); v[2] = f2bfu(f0.z); v[3] = f2bfu(f0.w);
            v[4] = f2bfu(f1.x); v[5] = f2bfu(f1.y); v[6] = f2bfu(f1.z); v[7] = f2bfu(f1.w);
        } else {
            const u16* p = (const u16*)Xin + (size_t)rg * DIN + col;
            ushort4 a = *(const ushort4*)p;
            ushort4 b = *(const ushort4*)(p + 4);
            v[0] = a.x; v[1] = a.y; v[2] = a.z; v[3] = a.w;
            v[4] = b.x; v[5] = b.y; v[6] = b.z; v[7] = b.w;
        }
        u16* d = &Xs[row * STRIDE + col];
#pragma unroll
        for (int j = 0; j < 8; j++) d[j] = v[j];
    }
    __syncthreads();

#pragma unroll
    for (int rt = 0; rt < 4; rt++) {
        short8 afr[KS];
#pragma unroll
        for (int ks = 0; ks < KS; ks++)
            afr[ks] = *(const short8*)&Xs[(rt * 16 + l15) * STRIDE + ks * 32 + quad * 8];
#pragma unroll
        for (int ct = 0; ct < TPW; ct++) {
            f32x4 cf = {0.f, 0.f, 0.f, 0.f};
#pragma unroll
            for (int ks = 0; ks < KS; ks++)
                cf = __builtin_amdgcn_mfma_f32_16x16x32_bf16(afr[ks], bfr[ct][ks], cf, 0, 0, 0);
            int col = (wave * TPW + ct) * 16 + l15;
            int rbase = n0 + rt * 16 + quad * 4;
#pragma unroll
            for (int reg = 0; reg < 4; reg++) {
                int r = rbase + reg;
                if (r < NN) Hb[(size_t)r * DOUT + col] = f2bfu(cf[reg]);
            }
        }
    }
}

// ================= fused softmax + aggregation (layers 1,2): wave per dst node =================
// bf16 out; fused next-layer s,t projection from f32 accumulators.
template<int DOUT>
__global__ void k_agg(const int* __restrict__ rowptr, const int* __restrict__ srcsort,
                      const float* __restrict__ s, const float* __restrict__ t,
                      const u16* __restrict__ Hb, const float* __restrict__ bias,
                      u16* __restrict__ OUT, const float* __restrict__ wan,
                      const float* __restrict__ wbn, float* __restrict__ sout,
                      float* __restrict__ tout) {
    constexpr int R = DOUT / 64;
    int node = blockIdx.x * 4 + (threadIdx.x >> 6);
    int lane = threadIdx.x & 63;
    if (node >= NN) return;
    int beg = rowptr[node], end = rowptr[node + 1];
    float tn = t[node];
    int j0 = beg + lane;
    float ex0 = 0.f; int sv0 = 0;
    if (j0 < end) {
        sv0 = srcsort[j0];
        float e = s[sv0] + tn;
        e = (e > 0.f) ? e : 0.2f * e;
        ex0 = expf(e);
    }
    float dsum = ex0;
    for (int j = j0 + 64; j < end; j += 64) {
        float e = s[srcsort[j]] + tn;
        e = (e > 0.f) ? e : 0.2f * e;
        dsum += expf(e);
    }
#pragma unroll
    for (int off = 32; off; off >>= 1) dsum += __shfl_xor(dsum, off);
    float inv = 1.f / dsum;
    float acc[R];
#pragma unroll
    for (int o = 0; o < R; o++) acc[o] = bias[lane * R + o];

    auto gather = [&](float exv, int svv, int cnt) {
        int q = 0;
        for (; q + 4 <= cnt; q += 4) {
            float a0 = __shfl(exv, q),     a1 = __shfl(exv, q + 1);
            float a2 = __shfl(exv, q + 2), a3 = __shfl(exv, q + 3);
            int i0 = __shfl(svv, q),     i1 = __shfl(svv, q + 1);
            int i2 = __shfl(svv, q + 2), i3 = __shfl(svv, q + 3);
            if constexpr (R == 2) {
                ushort2 u0 = *(const ushort2*)(Hb + (size_t)i0 * DOUT + lane * 2);
                ushort2 u1 = *(const ushort2*)(Hb + (size_t)i1 * DOUT + lane * 2);
                ushort2 u2 = *(const ushort2*)(Hb + (size_t)i2 * DOUT + lane * 2);
                ushort2 u3 = *(const ushort2*)(Hb + (size_t)i3 * DOUT + lane * 2);
                acc[0] += a0 * bfu2f(u0.x); acc[1] += a0 * bfu2f(u0.y);
                acc[0] += a1 * bfu2f(u1.x); acc[1] += a1 * bfu2f(u1.y);
                acc[0] += a2 * bfu2f(u2.x); acc[1] += a2 * bfu2f(u2.y);
                acc[0] += a3 * bfu2f(u3.x); acc[1] += a3 * bfu2f(u3.y);
            } else {
                u16 u0 = Hb[(size_t)i0 * DOUT + lane];
                u16 u1 = Hb[(size_t)i1 * DOUT + lane];
                u16 u2 = Hb[(size_t)i2 * DOUT + lane];
                u16 u3 = Hb[(size_t)i3 * DOUT + lane];
                acc[0] += a0 * bfu2f(u0) + a1 * bfu2f(u1) + a2 * bfu2f(u2) + a3 * bfu2f(u3);
            }
        }
        for (; q < cnt; q++) {
            float a = __shfl(exv, q);
            int  i = __shfl(svv, q);
            const u16* hrow = Hb + (size_t)i * DOUT + lane * R;
            if constexpr (R == 2) {
                ushort2 u = *(const ushort2*)hrow;
                acc[0] += a * bfu2f(u.x); acc[1] += a * bfu2f(u.y);
            } else {
                acc[0] += a * bfu2f(hrow[0]);
            }
        }
    };

    gather(ex0 * inv, sv0, min(64, end - beg));
    for (int cbeg = beg + 64; cbeg < end; cbeg += 64) {
        int j = cbeg + lane;
        float ex = 0.f; int sv = 0;
        if (j < end) {
            sv = srcsort[j];
            float e = s[sv] + tn;
            e = (e > 0.f) ? e : 0.2f * e;
            ex = expf(e) * inv;
        }
        gather(ex, sv, min(64, end - cbeg));
    }

    // fused next-layer projections from f32 accumulators
    {
        float pa = 0.f, pb = 0.f;
#pragma unroll
        for (int o = 0; o < R; o++) {
            pa += acc[o] * wan[lane * R + o];
            pb += acc[o] * wbn[lane * R + o];
        }
#pragma unroll
        for (int off = 32; off; off >>= 1) {
            pa += __shfl_xor(pa, off);
            pb += __shfl_xor(pb, off);
        }
        if (lane == 0) { sout[node] = pa; tout[node] = pb; }
    }

    u16* orow = OUT + (size_t)node * DOUT + lane * R;
    if constexpr (R == 2) {
        union { ushort2 u2; unsigned u; } p;
        p.u2.x = f2bfu(acc[0]); p.u2.y = f2bfu(acc[1]);
        *(unsigned*)orow = p.u;
    } else {
        orow[0] = f2bfu(acc[0]);
    }
}

// ================= layer-3 aggregation, column-split halves (grid.y = 2) =================
__global__ void k_agg256h(const int* __restrict__ rowptr, const int* __restrict__ srcsort,
                          const float* __restrict__ s, const float* __restrict__ t,
                          const u16* __restrict__ Hb, const float* __restrict__ bias,
                          u16* __restrict__ OUT) {
    int node = blockIdx.x * 4 + (threadIdx.x >> 6);
    int lane = threadIdx.x & 63;
    int half = blockIdx.y;
    if (node >= NN) return;
    int beg = rowptr[node], end = rowptr[node + 1];
    float tn = t[node];
    int j0 = beg + lane;
    float ex0 = 0.f; int sv0 = 0;
    if (j0 < end) {
        sv0 = srcsort[j0];
        float e = s[sv0] + tn;
        e = (e > 0.f) ? e : 0.2f * e;
        ex0 = expf(e);
    }
    float dsum = ex0;
    for (int j = j0 + 64; j < end; j += 64) {
        float e = s[srcsort[j]] + tn;
        e = (e > 0.f) ? e : 0.2f * e;
        dsum += expf(e);
    }
#pragma unroll
    for (int off = 32; off; off >>= 1) dsum += __shfl_xor(dsum, off);
    float inv = 1.f / dsum;
    int cb = half * 128 + lane * 2;
    float acc0 = bias[cb], acc1 = bias[cb + 1];
    const u16* Hbh = Hb + cb;

    auto gather = [&](float exv, int svv, int cnt) {
        int q = 0;
        for (; q + 4 <= cnt; q += 4) {
            float a0 = __shfl(exv, q),     a1 = __shfl(exv, q + 1);
            float a2 = __shfl(exv, q + 2), a3 = __shfl(exv, q + 3);
            int i0 = __shfl(svv, q),     i1 = __shfl(svv, q + 1);
            int i2 = __shfl(svv, q + 2), i3 = __shfl(svv, q + 3);
            ushort2 u0 = *(const ushort2*)(Hbh + (size_t)i0 * 256);
            ushort2 u1 = *(const ushort2*)(Hbh + (size_t)i1 * 256);
            ushort2 u2 = *(const ushort2*)(Hbh + (size_t)i2 * 256);
            ushort2 u3 = *(const ushort2*)(Hbh + (size_t)i3 * 256);
            acc0 += a0 * bfu2f(u0.x); acc1 += a0 * bfu2f(u0.y);
            acc0 += a1 * bfu2f(u1.x); acc1 += a1 * bfu2f(u1.y);
            acc0 += a2 * bfu2f(u2.x); acc1 += a2 * bfu2f(u2.y);
            acc0 += a3 * bfu2f(u3.x); acc1 += a3 * bfu2f(u3.y);
        }
        for (; q < cnt; q++) {
            float a = __shfl(exv, q);
            int  i = __shfl(svv, q);
            ushort2 u = *(const ushort2*)(Hbh + (size_t)i * 256);
            acc0 += a * bfu2f(u.x); acc1 += a * bfu2f(u.y);
        }
    };

    gather(ex0 * inv, sv0, min(64, end - beg));
    for (int cbeg = beg + 64; cbeg < end; cbeg += 64) {
        int j = cbeg + lane;
        float ex = 0.f; int sv = 0;
        if (j < end) {
            sv = srcsort[j];
            float e = s[sv] + tn;
            e = (e > 0.f) ? e : 0.2f * e;
            ex = expf(e) * inv;
        }
        gather(ex, sv, min(64, end - cbeg));
    }

    union { ushort2 u2; unsigned u; } p;
    p.u2.x = f2bfu(acc0); p.u2.y = f2bfu(acc1);
    *(unsigned*)(OUT + (size_t)node * 256 + cb) = p.u;
}

// ================= pooling (bf16 input) =================
__global__ void k_pool2(const u16* __restrict__ H, const int* __restrict__ batch,
                        unsigned* __restrict__ x1k, float* __restrict__ x2,
                        float* __restrict__ cnt) {
    int c0 = blockIdx.x * 64;
    if (c0 >= NN) return;
    int o = threadIdx.x;
    int endn = min(c0 + 64, NN);
    int g = batch[c0];
    float mx = -INFINITY, sm = 0.f, cl = 0.f;
    for (int nd = c0; nd < endn; nd++) {
        int bg = batch[nd];
        if (bg != g) {
            atomicMax(&x1k[g * 256 + o], fkey(mx));
            atomicAdd(&x2[g * 256 + o], sm);
            if (o == 0) atomicAdd(&cnt[g], cl);
            g = bg; mx = -INFINITY; sm = 0.f; cl = 0.f;
        }
        float hv = bfu2f(H[(size_t)nd * 256 + o]);
        mx = fmaxf(mx, hv);
        sm += hv;
        cl += 1.f;
    }
    atomicMax(&x1k[g * 256 + o], fkey(mx));
    atomicAdd(&x2[g * 256 + o], sm);
    if (o == 0) atomicAdd(&cnt[g], cl);
}

// ================= fused dense tail =================
template<int DIN, int DOUT, int ACT>
__device__ __forceinline__ void dense_layer(const float* __restrict__ in,
                                            const float* __restrict__ W,
                                            const float* __restrict__ B,
                                            float* __restrict__ out, int o,
                                            float* __restrict__ red) {
    constexpr int T = 256 / DOUT;
    constexpr int KS = DIN / T;
    int oo = o % DOUT;
    int kk = o / DOUT;
    int kbase = kk * KS;
    float p0 = 0.f, p1 = 0.f, p2 = 0.f, p3 = 0.f;
#pragma unroll 4
    for (int k = 0; k < KS; k += 4) {
        p0 += in[kbase + k]     * W[(size_t)(kbase + k) * DOUT + oo];
        p1 += in[kbase + k + 1] * W[(size_t)(kbase + k + 1) * DOUT + oo];
        p2 += in[kbase + k + 2] * W[(size_t)(kbase + k + 2) * DOUT + oo];
        p3 += in[kbase + k + 3] * W[(size_t)(kbase + k + 3) * DOUT + oo];
    }
    float p = (p0 + p1) + (p2 + p3);
    if constexpr (T > 1) {
        red[o] = p;
        __syncthreads();
        if (o < DOUT) {
#pragma unroll
            for (int tt = 1; tt < T; tt++) p += red[oo + tt * DOUT];
        }
    }
    if (o < DOUT) {
        p += B[oo];
        if constexpr (ACT == 1) p = fmaxf(p, 0.f);
        else if constexpr (ACT == 2) p = 1.f / (1.f + expf(-p));
        out[oo] = p;
    }
    __syncthreads();
}

__global__ void k_tail(const unsigned* __restrict__ x1k, const float* __restrict__ x2,
                       const float* __restrict__ cnt,
                       const float* __restrict__ d1w, const float* __restrict__ d1b,
                       const float* __restrict__ d2w, const float* __restrict__ d2b,
                       const float* __restrict__ d3w, const float* __restrict__ d3b,
                       const float* __restrict__ mw,  const float* __restrict__ mb,
                       const float* __restrict__ d4w, const float* __restrict__ d4b,
                       const float* __restrict__ d5w, const float* __restrict__ d5b,
                       const float* __restrict__ d6w, const float* __restrict__ d6b,
                       const float* __restrict__ d7w, const float* __restrict__ d7b,
                       float* __restrict__ out) {
    __shared__ float z[512];
    __shared__ float A[256];
    __shared__ float Bf[256];
    __shared__ float red[256];
    __shared__ float x3s[256];
    __shared__ float gbuf[64];
    int g = blockIdx.x, o = threadIdx.x;
    float c = fmaxf(cnt[g], 1.f);
    float sv = x2[(size_t)g * 256 + o];
    z[o] = fkey_inv(x1k[(size_t)g * 256 + o]);
    z[256 + o] = sv;
    x3s[o] = sv / c;
    __syncthreads();
    dense_layer<512, 256, 1>(z,   d1w, d1b, A,    o, red);
    dense_layer<256, 128, 1>(A,   d2w, d2b, Bf,   o, red);
    dense_layer<128,  64, 1>(Bf,  d3w, d3b, A,    o, red);
    dense_layer<256,  64, 2>(x3s, mw,  mb,  gbuf, o, red);
    if (o < 64) A[o] *= gbuf[o];
    __syncthreads();
    dense_layer< 64,  64, 1>(A,   d4w, d4b, Bf,   o, red);
    dense_layer< 64, 128, 1>(Bf,  d5w, d5b, A,    o, red);
    dense_layer<128, 256, 1>(A,   d6w, d6b, z,    o, red);
    dense_layer<256, 128, 0>(z,   d7w, d7b, A,    o, red);
    if (o < 128) out[(size_t)g * 128 + o] = A[o];
}

// =====================================================================
extern "C" void kernel_launch(void* const* d_in, const int* in_sizes, int n_in,
                              void* d_out, int out_size, void* d_ws, size_t ws_size,
                              hipStream_t stream) {
    const float* x_in  = (const float*)d_in[0];
    const int*   ei    = (const int*)d_in[1];
    const int*   batch = (const int*)d_in[2];
    const int* src = ei;
    const int* dst = ei + NE;

    const float* Wl[3]  = { (const float*)d_in[3], (const float*)d_in[7],  (const float*)d_in[11] };
    const float* asl[3] = { (const float*)d_in[4], (const float*)d_in[8],  (const float*)d_in[12] };
    const float* adl[3] = { (const float*)d_in[5], (const float*)d_in[9],  (const float*)d_in[13] };
    const float* bl[3]  = { (const float*)d_in[6], (const float*)d_in[10], (const float*)d_in[14] };

    const float* d1w = (const float*)d_in[15]; const float* d1b = (const float*)d_in[16];
    const float* d2w = (const float*)d_in[17]; const float* d2b = (const float*)d_in[18];
    const float* d3w = (const float*)d_in[19]; const float* d3b = (const float*)d_in[20];
    const float* mw  = (const float*)d_in[21]; const float* mb  = (const float*)d_in[22];
    const float* d4w = (const float*)d_in[23]; const float* d4b = (const float*)d_in[24];
    const float* d5w = (const float*)d_in[25]; const float* d5b = (const float*)d_in[26];
    const float* d6w = (const float*)d_in[27]; const float* d6b = (const float*)d_in[28];
    const float* d7w = (const float*)d_in[29]; const float* d7b = (const float*)d_in[30];

    // -------- workspace carve --------
    float* ws = (float*)d_ws;
    size_t off = 0;
    u16* Hb  = (u16*)(ws + off); off += (size_t)NN * 128;   // bf16 H [NN][<=256]
    u16* Xb  = (u16*)(ws + off); off += (size_t)NN * 64;    // bf16 activations [NN][<=128]
    u16* Xb3 = (u16*)(ws + off); off += (size_t)NN * 128;   // bf16 layer-3 out [NN][256]
    float* sA = ws + off; off += NN;
    float* tA = ws + off; off += NN;
    float* sB = ws + off; off += NN;
    float* tB = ws + off; off += NN;
    u16* Wb0 = (u16*)(ws + off); off += (128 * 64) / 2;
    u16* Wb1 = (u16*)(ws + off); off += (64 * 128) / 2;
    u16* Wb2 = (u16*)(ws + off); off += (128 * 256) / 2;
    float* wa0 = ws + off; off += 128;  float* wb0 = ws + off; off += 128;
    float* wa1 = ws + off; off += 64;   float* wb1 = ws + off; off += 64;
    float* wa2 = ws + off; off += 128;  float* wb2 = ws + off; off += 128;
    unsigned* x1k = (unsigned*)(ws + off); off += NG * 256;   // x1k,x2,cnt contiguous (zeroed together)
    float* x2    = ws + off; off += NG * 256;
    float* cnt   = ws + off; off += NG;
    int* ip      = (int*)(ws + off);
    int* deg     = ip;               ip += NN;
    int* excl    = ip;               ip += NN;
    int* partials= ip;               ip += SCAN_B;
    int* rowptr  = ip;               ip += NN + 1;
    int* cursor  = ip;               ip += NN;
    int* srcsort = ip;               ip += NEP;

    const int nb = (NN + SCAN_B - 1) / SCAN_B;
    const int GB = (NN + 63) / 64;      // gemm blocks
    const int AB = (NN + 3) / 4;        // agg/st blocks
    const int NZ = NN + NG * 512 + NG;  // zero: deg + pool buffers

    // -------- init + CSR build --------
    k_zero2<<<(NZ + 255) / 256, 256, 0, stream>>>(deg, NN, (int*)x1k, NG * 512 + NG);
    k_hist<<<(NEP + 255) / 256, 256, 0, stream>>>(dst, deg);
    k_scan1<<<nb, SCAN_B, 0, stream>>>(deg, excl, partials, NN);
    k_scan2<<<1, SCAN_B, 0, stream>>>(partials, nb);
    k_scan3<<<nb, SCAN_B, 0, stream>>>(excl, partials, rowptr, cursor, NN);
    k_scatter<<<(NEP + 255) / 256, 256, 0, stream>>>(src, dst, cursor, srcsort);

    // -------- weight prep (all layers, one launch) --------
    k_prep3<<<320, 256, 0, stream>>>(Wl[0], asl[0], adl[0], Wb0, wa0, wb0,
                                     Wl[1], asl[1], adl[1], Wb1, wa1, wb1,
                                     Wl[2], asl[2], adl[2], Wb2, wa2, wb2);

    // -------- layer 1: x_in(f32,128) -> Hb(64) -> Xb(bf16,64); s2,t2 fused --------
    k_st128<<<AB, 256, 0, stream>>>(x_in, wa0, wb0, sA, tA);
    k_gemm_mfma<128, 64, true><<<GB, 256, 0, stream>>>(x_in, Wb0, Hb);
    k_agg<64><<<AB, 256, 0, stream>>>(rowptr, srcsort, sA, tA, Hb, bl[0], Xb, wa1, wb1, sB, tB);

    // -------- layer 2: Xb(64) -> Hb(128) -> Xb(bf16,128); s3,t3 fused --------
    k_gemm_mfma<64, 128, false><<<GB, 256, 0, stream>>>(Xb, Wb1, Hb);
    k_agg<128><<<AB, 256, 0, stream>>>(rowptr, srcsort, sB, tB, Hb, bl[1], Xb, wa2, wb2, sA, tA);

    // -------- layer 3: Xb(128) -> Hb(256) -> Xb3(bf16,256), column-split halves --------
    k_gemm_mfma<128, 256, false><<<GB, 256, 0, stream>>>(Xb, Wb2, Hb);
    k_agg256h<<<dim3(AB, 2), 256, 0, stream>>>(rowptr, srcsort, sA, tA, Hb, bl[2], Xb3);

    // -------- pooling + fused tail --------
    k_pool2<<<(NN + 63) / 64, 256, 0, stream>>>(Xb3, batch, x1k, x2, cnt);
    k_tail<<<NG, 256, 0, stream>>>(x1k, x2, cnt,
                                   d1w, d1b, d2w, d2b, d3w, d3b, mw, mb,
                                   d4w, d4b, d5w, d5b, d6w, d6b, d7w, d7b,
                                   (float*)d_out);
}

// Round 10
// 447.446 us; speedup vs baseline: 5.7010x; 1.0194x over previous
//
#include <hip/hip_runtime.h>
#include <hip/hip_bf16.h>
#include <math.h>

#define NN 50000      // nodes
#define NE 800000     // edges (without self loops)
#define NEP 850000    // edges + self loops
#define NG 64         // graphs
#define SCAN_B 256

typedef unsigned short u16;
typedef __attribute__((ext_vector_type(8))) short short8;    // 8 bf16 (4 VGPRs) MFMA A/B frag
typedef __attribute__((ext_vector_type(4))) float f32x4;     // MFMA C/D frag

__device__ __forceinline__ float bfu2f(u16 u) {
    return __uint_as_float((unsigned)u << 16);
}
__device__ __forceinline__ u16 f2bfu(float f) {
    __hip_bfloat16 h = __float2bfloat16(f);   // RTNE
    union { __hip_bfloat16 h; u16 u; } c; c.h = h; return c.u;
}

// order-preserving float -> uint key
__device__ __forceinline__ unsigned fkey(float f) {
    unsigned u = __float_as_uint(f);
    return (u & 0x80000000u) ? ~u : (u | 0x80000000u);
}
__device__ __forceinline__ float fkey_inv(unsigned k) {
    return (k & 0x80000000u) ? __uint_as_float(k ^ 0x80000000u) : __uint_as_float(~k);
}

// ================= init: zero two int regions in one launch =================
__global__ void k_zero2(int* __restrict__ a, int na, int* __restrict__ b, int nb) {
    int i = blockIdx.x * blockDim.x + threadIdx.x;
    if (i < na) a[i] = 0;
    else if (i - na < nb) b[i - na] = 0;
}

// ================= CSR build =================
__global__ void k_hist(const int* __restrict__ dst, int* __restrict__ deg) {
    int i = blockIdx.x * blockDim.x + threadIdx.x;
    if (i >= NEP) return;
    int dv = (i < NE) ? dst[i] : (i - NE);
    atomicAdd(&deg[dv], 1);
}

__global__ void k_scan1(const int* __restrict__ deg, int* __restrict__ excl,
                        int* __restrict__ partials, int n) {
    __shared__ int sh[SCAN_B];
    int i = blockIdx.x * SCAN_B + threadIdx.x;
    int v = (i < n) ? deg[i] : 0;
    sh[threadIdx.x] = v;
    __syncthreads();
    for (int off = 1; off < SCAN_B; off <<= 1) {
        int t = (threadIdx.x >= off) ? sh[threadIdx.x - off] : 0;
        __syncthreads();
        sh[threadIdx.x] += t;
        __syncthreads();
    }
    if (i < n) excl[i] = sh[threadIdx.x] - v;
    if (threadIdx.x == SCAN_B - 1) partials[blockIdx.x] = sh[threadIdx.x];
}

__global__ void k_scan2(int* __restrict__ partials, int nb) {  // single block
    __shared__ int sh[SCAN_B];
    int v = (threadIdx.x < nb) ? partials[threadIdx.x] : 0;
    sh[threadIdx.x] = v;
    __syncthreads();
    for (int off = 1; off < SCAN_B; off <<= 1) {
        int t = (threadIdx.x >= off) ? sh[threadIdx.x - off] : 0;
        __syncthreads();
        sh[threadIdx.x] += t;
        __syncthreads();
    }
    if (threadIdx.x < nb) partials[threadIdx.x] = sh[threadIdx.x] - v;
}

__global__ void k_scan3(const int* __restrict__ excl, const int* __restrict__ partials,
                        int* __restrict__ rowptr, int* __restrict__ cursor, int n) {
    int i = blockIdx.x * SCAN_B + threadIdx.x;
    if (i < n) {
        int r = excl[i] + partials[blockIdx.x];
        rowptr[i] = r;
        cursor[i] = r;
    }
    if (i == 0) rowptr[n] = NEP;
}

__global__ void k_scatter(const int* __restrict__ src, const int* __restrict__ dst,
                          int* __restrict__ cursor, int* __restrict__ srcsort) {
    int i = blockIdx.x * blockDim.x + threadIdx.x;
    if (i >= NEP) return;
    int sv = (i < NE) ? src[i] : (i - NE);
    int dv = (i < NE) ? dst[i] : (i - NE);
    int pos = atomicAdd(&cursor[dv], 1);
    srcsort[pos] = sv;
}

// ================= merged layer prep: Wb = bf16(W); wa = W.asv, wb = W.adv =================
__global__ void k_prep3(const float* __restrict__ W0, const float* __restrict__ as0, const float* __restrict__ ad0,
                        u16* __restrict__ Wb0, float* __restrict__ wa0, float* __restrict__ wb0,
                        const float* __restrict__ W1, const float* __restrict__ as1, const float* __restrict__ ad1,
                        u16* __restrict__ Wb1, float* __restrict__ wa1, float* __restrict__ wb1,
                        const float* __restrict__ W2, const float* __restrict__ as2, const float* __restrict__ ad2,
                        u16* __restrict__ Wb2, float* __restrict__ wa2, float* __restrict__ wb2) {
    __shared__ float pas[4], pbs[4];
    int b = blockIdx.x, tid = threadIdx.x;
    const float *W, *asv, *adv; u16* Wb; float *wa, *wb; int k, dout;
    if (b < 128)      { W = W0; asv = as0; adv = ad0; Wb = Wb0; wa = wa0; wb = wb0; k = b;       dout = 64;  }
    else if (b < 192) { W = W1; asv = as1; adv = ad1; Wb = Wb1; wa = wa1; wb = wb1; k = b - 128; dout = 128; }
    else              { W = W2; asv = as2; adv = ad2; Wb = Wb2; wa = wa2; wb = wb2; k = b - 192; dout = 256; }
    float pa = 0.f, pb = 0.f;
    for (int n = tid; n < dout; n += 256) {
        float w = W[(size_t)k * dout + n];
        Wb[(size_t)k * dout + n] = f2bfu(w);
        pa += w * asv[n];
        pb += w * adv[n];
    }
#pragma unroll
    for (int off = 32; off; off >>= 1) {
        pa += __shfl_xor(pa, off);
        pb += __shfl_xor(pb, off);
    }
    if ((tid & 63) == 0) { pas[tid >> 6] = pa; pbs[tid >> 6] = pb; }
    __syncthreads();
    if (tid == 0) {
        wa[k] = pas[0] + pas[1] + pas[2] + pas[3];
        wb[k] = pbs[0] + pbs[1] + pbs[2] + pbs[3];
    }
}

// ================= s,t = X . wa, X . wb  (layer 1 only; wave per node) =================
__global__ void k_st128(const float* __restrict__ Xin, const float* __restrict__ wa,
                        const float* __restrict__ wb, float* __restrict__ s,
                        float* __restrict__ t) {
    int node = blockIdx.x * 4 + (threadIdx.x >> 6);
    int lane = threadIdx.x & 63;
    const float* p = Xin + (size_t)node * 128 + lane * 2;
    float x0 = p[0], x1 = p[1];
    float pa = x0 * wa[lane * 2] + x1 * wa[lane * 2 + 1];
    float pb = x0 * wb[lane * 2] + x1 * wb[lane * 2 + 1];
#pragma unroll
    for (int off = 32; off; off >>= 1) {
        pa += __shfl_xor(pa, off);
        pb += __shfl_xor(pb, off);
    }
    if (lane == 0) { s[node] = pa; t[node] = pb; }
}

// ================= MFMA GEMM: Hb[NN,DOUT](bf16) = X[NN,DIN] @ Wb[DIN,DOUT] =================
template<int DIN, int DOUT, bool XF32>
__global__ __launch_bounds__(256) void k_gemm_mfma(const void* __restrict__ Xin,
                                                   const u16* __restrict__ Wb,
                                                   u16* __restrict__ Hb) {
    constexpr int KS = DIN / 32;
    constexpr int CT = DOUT / 16;
    constexpr int TPW = CT / 4;
    constexpr int STRIDE = DIN + 16;
    __shared__ u16 Xs[64 * STRIDE];
    int tid = threadIdx.x, wave = tid >> 6, lane = tid & 63;
    int quad = lane >> 4, l15 = lane & 15;
    int n0 = blockIdx.x * 64;

    short8 bfr[TPW][KS];
#pragma unroll
    for (int ct = 0; ct < TPW; ct++) {
        int nb = (wave * TPW + ct) * 16 + l15;
#pragma unroll
        for (int ks = 0; ks < KS; ks++) {
            int kb = ks * 32 + quad * 8;
            short8 b;
#pragma unroll
            for (int j = 0; j < 8; j++) b[j] = (short)Wb[(size_t)(kb + j) * DOUT + nb];
            bfr[ct][ks] = b;
        }
    }

    for (int c = tid; c < 64 * DIN / 8; c += 256) {
        int row = (c * 8) / DIN, col = (c * 8) % DIN;
        int rg = n0 + row; if (rg >= NN) rg = NN - 1;
        u16 v[8];
        if constexpr (XF32) {
            const float* p = (const float*)Xin + (size_t)rg * DIN + col;
            float4 f0 = *(const float4*)p;
            float4 f1 = *(const float4*)(p + 4);
            v[0] = f2bfu(f0.x); v[1] = f2bfu(f0.y); v[2] = f2bfu(f0.z); v[3] = f2bfu(f0.w);
            v[4] = f2bfu(f1.x); v[5] = f2bfu(f1.y); v[6] = f2bfu(f1.z); v[7] = f2bfu(f1.w);
        } else {
            const u16* p = (const u16*)Xin + (size_t)rg * DIN + col;
            ushort4 a = *(const ushort4*)p;
            ushort4 b = *(const ushort4*)(p + 4);
            v[0] = a.x; v[1] = a.y; v[2] = a.z; v[3] = a.w;
            v[4] = b.x; v[5] = b.y; v[6] = b.z; v[7] = b.w;
        }
        u16* d = &Xs[row * STRIDE + col];
#pragma unroll
        for (int j = 0; j < 8; j++) d[j] = v[j];
    }
    __syncthreads();

#pragma unroll
    for (int rt = 0; rt < 4; rt++) {
        short8 afr[KS];
#pragma unroll
        for (int ks = 0; ks < KS; ks++)
            afr[ks] = *(const short8*)&Xs[(rt * 16 + l15) * STRIDE + ks * 32 + quad * 8];
#pragma unroll
        for (int ct = 0; ct < TPW; ct++) {
            f32x4 cf = {0.f, 0.f, 0.f, 0.f};
#pragma unroll
            for (int ks = 0; ks < KS; ks++)
                cf = __builtin_amdgcn_mfma_f32_16x16x32_bf16(afr[ks], bfr[ct][ks], cf, 0, 0, 0);
            int col = (wave * TPW + ct) * 16 + l15;
            int rbase = n0 + rt * 16 + quad * 4;
#pragma unroll
            for (int reg = 0; reg < 4; reg++) {
                int r = rbase + reg;
                if (r < NN) Hb[(size_t)r * DOUT + col] = f2bfu(cf[reg]);
            }
        }
    }
}

// ================= multi-edge aggregation (layers 1,2): wave per dst node =================
// P = 64/(DOUT/8) edges processed in parallel; each DOUT/8-lane subgroup loads one
// full row with 16B uint4 loads. Fused next-layer s,t projection.
template<int DOUT>
__global__ void k_agg_w(const int* __restrict__ rowptr, const int* __restrict__ srcsort,
                        const float* __restrict__ s, const float* __restrict__ t,
                        const u16* __restrict__ Hb, const float* __restrict__ bias,
                        u16* __restrict__ OUT, const float* __restrict__ wan,
                        const float* __restrict__ wbn, float* __restrict__ sout,
                        float* __restrict__ tout) {
    constexpr int GS = DOUT / 8;      // lanes per edge-row
    constexpr int P  = 64 / GS;       // edges in parallel
    int node = blockIdx.x * 4 + (threadIdx.x >> 6);
    int lane = threadIdx.x & 63;
    if (node >= NN) return;
    int sg = lane / GS;               // subgroup (edge slot)
    int pg = lane % GS;               // position in row (8 cols each)
    int beg = rowptr[node], end = rowptr[node + 1];
    float tn = t[node];
    // phase 1: denominator; keep first-chunk values in registers
    int j0 = beg + lane;
    float ex0 = 0.f; int sv0 = 0;
    if (j0 < end) {
        sv0 = srcsort[j0];
        float e = s[sv0] + tn;
        e = (e > 0.f) ? e : 0.2f * e;
        ex0 = expf(e);
    }
    float dsum = ex0;
    for (int j = j0 + 64; j < end; j += 64) {
        float e = s[srcsort[j]] + tn;
        e = (e > 0.f) ? e : 0.2f * e;
        dsum += expf(e);
    }
#pragma unroll
    for (int off = 32; off; off >>= 1) dsum += __shfl_xor(dsum, off);
    float inv = 1.f / dsum;

    float acc[8];
#pragma unroll
    for (int e = 0; e < 8; e++) acc[e] = 0.f;

    auto gather = [&](float exv, int svv, int cnt) {
        for (int q = 0; q < cnt; q += P) {
            int myq = q + sg;
            int mq = (myq < cnt) ? myq : q;
            float a = __shfl(exv, mq);
            int  idx = __shfl(svv, mq);
            if (myq >= cnt) a = 0.f;
            uint4 u = *(const uint4*)(Hb + (size_t)idx * DOUT + pg * 8);
            acc[0] += a * bfu2f((u16)(u.x & 0xffff));
            acc[1] += a * bfu2f((u16)(u.x >> 16));
            acc[2] += a * bfu2f((u16)(u.y & 0xffff));
            acc[3] += a * bfu2f((u16)(u.y >> 16));
            acc[4] += a * bfu2f((u16)(u.z & 0xffff));
            acc[5] += a * bfu2f((u16)(u.z >> 16));
            acc[6] += a * bfu2f((u16)(u.w & 0xffff));
            acc[7] += a * bfu2f((u16)(u.w >> 16));
        }
    };

    gather(ex0 * inv, sv0, min(64, end - beg));
    for (int cbeg = beg + 64; cbeg < end; cbeg += 64) {
        int j = cbeg + lane;
        float ex = 0.f; int sv = 0;
        if (j < end) {
            sv = srcsort[j];
            float e = s[sv] + tn;
            e = (e > 0.f) ? e : 0.2f * e;
            ex = expf(e) * inv;
        }
        gather(ex, sv, min(64, end - cbeg));
    }

    // combine subgroup partials: after this every lane holds the full sum for its pg cols
#pragma unroll
    for (int step = GS; step < 64; step <<= 1) {
#pragma unroll
        for (int e = 0; e < 8; e++) acc[e] += __shfl_xor(acc[e], step);
    }
    // add bias -> final h for cols pg*8..pg*8+7
#pragma unroll
    for (int e = 0; e < 8; e++) acc[e] += bias[pg * 8 + e];

    // fused next-layer projections (every lane duplicates its pg class P times -> /P)
    {
        float pa = 0.f, pb = 0.f;
#pragma unroll
        for (int e = 0; e < 8; e++) {
            pa += acc[e] * wan[pg * 8 + e];
            pb += acc[e] * wbn[pg * 8 + e];
        }
#pragma unroll
        for (int off = 32; off; off >>= 1) {
            pa += __shfl_xor(pa, off);
            pb += __shfl_xor(pb, off);
        }
        if (lane == 0) { sout[node] = pa * (1.f / P); tout[node] = pb * (1.f / P); }
    }

    if (sg == 0) {
        uint4 o;
        o.x = (unsigned)f2bfu(acc[0]) | ((unsigned)f2bfu(acc[1]) << 16);
        o.y = (unsigned)f2bfu(acc[2]) | ((unsigned)f2bfu(acc[3]) << 16);
        o.z = (unsigned)f2bfu(acc[4]) | ((unsigned)f2bfu(acc[5]) << 16);
        o.w = (unsigned)f2bfu(acc[6]) | ((unsigned)f2bfu(acc[7]) << 16);
        *(uint4*)(OUT + (size_t)node * DOUT + pg * 8) = o;
    }
}

// ================= layer-3 aggregation: full-row, ushort4/lane (R8 structure) =================
__global__ void k_agg256(const int* __restrict__ rowptr, const int* __restrict__ srcsort,
                         const float* __restrict__ s, const float* __restrict__ t,
                         const u16* __restrict__ Hb, const float* __restrict__ bias,
                         u16* __restrict__ OUT) {
    int node = blockIdx.x * 4 + (threadIdx.x >> 6);
    int lane = threadIdx.x & 63;
    if (node >= NN) return;
    int beg = rowptr[node], end = rowptr[node + 1];
    float tn = t[node];
    int j0 = beg + lane;
    float ex0 = 0.f; int sv0 = 0;
    if (j0 < end) {
        sv0 = srcsort[j0];
        float e = s[sv0] + tn;
        e = (e > 0.f) ? e : 0.2f * e;
        ex0 = expf(e);
    }
    float dsum = ex0;
    for (int j = j0 + 64; j < end; j += 64) {
        float e = s[srcsort[j]] + tn;
        e = (e > 0.f) ? e : 0.2f * e;
        dsum += expf(e);
    }
#pragma unroll
    for (int off = 32; off; off >>= 1) dsum += __shfl_xor(dsum, off);
    float inv = 1.f / dsum;
    float acc0 = bias[lane * 4], acc1 = bias[lane * 4 + 1];
    float acc2 = bias[lane * 4 + 2], acc3 = bias[lane * 4 + 3];

    auto gather = [&](float exv, int svv, int cnt) {
        int q = 0;
        for (; q + 4 <= cnt; q += 4) {
            float a0 = __shfl(exv, q),     a1 = __shfl(exv, q + 1);
            float a2 = __shfl(exv, q + 2), a3 = __shfl(exv, q + 3);
            int i0 = __shfl(svv, q),     i1 = __shfl(svv, q + 1);
            int i2 = __shfl(svv, q + 2), i3 = __shfl(svv, q + 3);
            ushort4 u0 = *(const ushort4*)(Hb + (size_t)i0 * 256 + lane * 4);
            ushort4 u1 = *(const ushort4*)(Hb + (size_t)i1 * 256 + lane * 4);
            ushort4 u2 = *(const ushort4*)(Hb + (size_t)i2 * 256 + lane * 4);
            ushort4 u3 = *(const ushort4*)(Hb + (size_t)i3 * 256 + lane * 4);
            acc0 += a0 * bfu2f(u0.x); acc1 += a0 * bfu2f(u0.y);
            acc2 += a0 * bfu2f(u0.z); acc3 += a0 * bfu2f(u0.w);
            acc0 += a1 * bfu2f(u1.x); acc1 += a1 * bfu2f(u1.y);
            acc2 += a1 * bfu2f(u1.z); acc3 += a1 * bfu2f(u1.w);
            acc0 += a2 * bfu2f(u2.x); acc1 += a2 * bfu2f(u2.y);
            acc2 += a2 * bfu2f(u2.z); acc3 += a2 * bfu2f(u2.w);
            acc0 += a3 * bfu2f(u3.x); acc1 += a3 * bfu2f(u3.y);
            acc2 += a3 * bfu2f(u3.z); acc3 += a3 * bfu2f(u3.w);
        }
        for (; q < cnt; q++) {
            float a = __shfl(exv, q);
            int  i = __shfl(svv, q);
            ushort4 u = *(const ushort4*)(Hb + (size_t)i * 256 + lane * 4);
            acc0 += a * bfu2f(u.x); acc1 += a * bfu2f(u.y);
            acc2 += a * bfu2f(u.z); acc3 += a * bfu2f(u.w);
        }
    };

    gather(ex0 * inv, sv0, min(64, end - beg));
    for (int cbeg = beg + 64; cbeg < end; cbeg += 64) {
        int j = cbeg + lane;
        float ex = 0.f; int sv = 0;
        if (j < end) {
            sv = srcsort[j];
            float e = s[sv] + tn;
            e = (e > 0.f) ? e : 0.2f * e;
            ex = expf(e) * inv;
        }
        gather(ex, sv, min(64, end - cbeg));
    }

    ushort4 o;
    o.x = f2bfu(acc0); o.y = f2bfu(acc1); o.z = f2bfu(acc2); o.w = f2bfu(acc3);
    *(ushort4*)(OUT + (size_t)node * 256 + lane * 4) = o;
}

// ================= pooling (bf16 input) =================
__global__ void k_pool2(const u16* __restrict__ H, const int* __restrict__ batch,
                        unsigned* __restrict__ x1k, float* __restrict__ x2,
                        float* __restrict__ cnt) {
    int c0 = blockIdx.x * 64;
    if (c0 >= NN) return;
    int o = threadIdx.x;
    int endn = min(c0 + 64, NN);
    int g = batch[c0];
    float mx = -INFINITY, sm = 0.f, cl = 0.f;
    for (int nd = c0; nd < endn; nd++) {
        int bg = batch[nd];
        if (bg != g) {
            atomicMax(&x1k[g * 256 + o], fkey(mx));
            atomicAdd(&x2[g * 256 + o], sm);
            if (o == 0) atomicAdd(&cnt[g], cl);
            g = bg; mx = -INFINITY; sm = 0.f; cl = 0.f;
        }
        float hv = bfu2f(H[(size_t)nd * 256 + o]);
        mx = fmaxf(mx, hv);
        sm += hv;
        cl += 1.f;
    }
    atomicMax(&x1k[g * 256 + o], fkey(mx));
    atomicAdd(&x2[g * 256 + o], sm);
    if (o == 0) atomicAdd(&cnt[g], cl);
}

// ================= fused dense tail =================
template<int DIN, int DOUT, int ACT>
__device__ __forceinline__ void dense_layer(const float* __restrict__ in,
                                            const float* __restrict__ W,
                                            const float* __restrict__ B,
                                            float* __restrict__ out, int o,
                                            float* __restrict__ red) {
    constexpr int T = 256 / DOUT;
    constexpr int KS = DIN / T;
    int oo = o % DOUT;
    int kk = o / DOUT;
    int kbase = kk * KS;
    float p0 = 0.f, p1 = 0.f, p2 = 0.f, p3 = 0.f;
#pragma unroll 4
    for (int k = 0; k < KS; k += 4) {
        p0 += in[kbase + k]     * W[(size_t)(kbase + k) * DOUT + oo];
        p1 += in[kbase + k + 1] * W[(size_t)(kbase + k + 1) * DOUT + oo];
        p2 += in[kbase + k + 2] * W[(size_t)(kbase + k + 2) * DOUT + oo];
        p3 += in[kbase + k + 3] * W[(size_t)(kbase + k + 3) * DOUT + oo];
    }
    float p = (p0 + p1) + (p2 + p3);
    if constexpr (T > 1) {
        red[o] = p;
        __syncthreads();
        if (o < DOUT) {
#pragma unroll
            for (int tt = 1; tt < T; tt++) p += red[oo + tt * DOUT];
        }
    }
    if (o < DOUT) {
        p += B[oo];
        if constexpr (ACT == 1) p = fmaxf(p, 0.f);
        else if constexpr (ACT == 2) p = 1.f / (1.f + expf(-p));
        out[oo] = p;
    }
    __syncthreads();
}

__global__ void k_tail(const unsigned* __restrict__ x1k, const float* __restrict__ x2,
                       const float* __restrict__ cnt,
                       const float* __restrict__ d1w, const float* __restrict__ d1b,
                       const float* __restrict__ d2w, const float* __restrict__ d2b,
                       const float* __restrict__ d3w, const float* __restrict__ d3b,
                       const float* __restrict__ mw,  const float* __restrict__ mb,
                       const float* __restrict__ d4w, const float* __restrict__ d4b,
                       const float* __restrict__ d5w, const float* __restrict__ d5b,
                       const float* __restrict__ d6w, const float* __restrict__ d6b,
                       const float* __restrict__ d7w, const float* __restrict__ d7b,
                       float* __restrict__ out) {
    __shared__ float z[512];
    __shared__ float A[256];
    __shared__ float Bf[256];
    __shared__ float red[256];
    __shared__ float x3s[256];
    __shared__ float gbuf[64];
    int g = blockIdx.x, o = threadIdx.x;
    float c = fmaxf(cnt[g], 1.f);
    float sv = x2[(size_t)g * 256 + o];
    z[o] = fkey_inv(x1k[(size_t)g * 256 + o]);
    z[256 + o] = sv;
    x3s[o] = sv / c;
    __syncthreads();
    dense_layer<512, 256, 1>(z,   d1w, d1b, A,    o, red);
    dense_layer<256, 128, 1>(A,   d2w, d2b, Bf,   o, red);
    dense_layer<128,  64, 1>(Bf,  d3w, d3b, A,    o, red);
    dense_layer<256,  64, 2>(x3s, mw,  mb,  gbuf, o, red);
    if (o < 64) A[o] *= gbuf[o];
    __syncthreads();
    dense_layer< 64,  64, 1>(A,   d4w, d4b, Bf,   o, red);
    dense_layer< 64, 128, 1>(Bf,  d5w, d5b, A,    o, red);
    dense_layer<128, 256, 1>(A,   d6w, d6b, z,    o, red);
    dense_layer<256, 128, 0>(z,   d7w, d7b, A,    o, red);
    if (o < 128) out[(size_t)g * 128 + o] = A[o];
}

// =====================================================================
extern "C" void kernel_launch(void* const* d_in, const int* in_sizes, int n_in,
                              void* d_out, int out_size, void* d_ws, size_t ws_size,
                              hipStream_t stream) {
    const float* x_in  = (const float*)d_in[0];
    const int*   ei    = (const int*)d_in[1];
    const int*   batch = (const int*)d_in[2];
    const int* src = ei;
    const int* dst = ei + NE;

    const float* Wl[3]  = { (const float*)d_in[3], (const float*)d_in[7],  (const float*)d_in[11] };
    const float* asl[3] = { (const float*)d_in[4], (const float*)d_in[8],  (const float*)d_in[12] };
    const float* adl[3] = { (const float*)d_in[5], (const float*)d_in[9],  (const float*)d_in[13] };
    const float* bl[3]  = { (const float*)d_in[6], (const float*)d_in[10], (const float*)d_in[14] };

    const float* d1w = (const float*)d_in[15]; const float* d1b = (const float*)d_in[16];
    const float* d2w = (const float*)d_in[17]; const float* d2b = (const float*)d_in[18];
    const float* d3w = (const float*)d_in[19]; const float* d3b = (const float*)d_in[20];
    const float* mw  = (const float*)d_in[21]; const float* mb  = (const float*)d_in[22];
    const float* d4w = (const float*)d_in[23]; const float* d4b = (const float*)d_in[24];
    const float* d5w = (const float*)d_in[25]; const float* d5b = (const float*)d_in[26];
    const float* d6w = (const float*)d_in[27]; const float* d6b = (const float*)d_in[28];
    const float* d7w = (const float*)d_in[29]; const float* d7b = (const float*)d_in[30];

    // -------- workspace carve --------
    float* ws = (float*)d_ws;
    size_t off = 0;
    u16* Hb  = (u16*)(ws + off); off += (size_t)NN * 128;   // bf16 H [NN][<=256]
    u16* Xb  = (u16*)(ws + off); off += (size_t)NN * 64;    // bf16 activations [NN][<=128]
    u16* Xb3 = (u16*)(ws + off); off += (size_t)NN * 128;   // bf16 layer-3 out [NN][256]
    float* sA = ws + off; off += NN;
    float* tA = ws + off; off += NN;
    float* sB = ws + off; off += NN;
    float* tB = ws + off; off += NN;
    u16* Wb0 = (u16*)(ws + off); off += (128 * 64) / 2;
    u16* Wb1 = (u16*)(ws + off); off += (64 * 128) / 2;
    u16* Wb2 = (u16*)(ws + off); off += (128 * 256) / 2;
    float* wa0 = ws + off; off += 128;  float* wb0 = ws + off; off += 128;
    float* wa1 = ws + off; off += 64;   float* wb1 = ws + off; off += 64;
    float* wa2 = ws + off; off += 128;  float* wb2 = ws + off; off += 128;
    unsigned* x1k = (unsigned*)(ws + off); off += NG * 256;
    float* x2    = ws + off; off += NG * 256;
    float* cnt   = ws + off; off += NG;
    int* ip      = (int*)(ws + off);
    int* deg     = ip;               ip += NN;
    int* excl    = ip;               ip += NN;
    int* partials= ip;               ip += SCAN_B;
    int* rowptr  = ip;               ip += NN + 1;
    int* cursor  = ip;               ip += NN;
    int* srcsort = ip;               ip += NEP;

    const int nb = (NN + SCAN_B - 1) / SCAN_B;
    const int GB = (NN + 63) / 64;      // gemm blocks
    const int AB = (NN + 3) / 4;        // agg/st blocks
    const int NZ = NN + NG * 512 + NG;

    // -------- init + CSR build --------
    k_zero2<<<(NZ + 255) / 256, 256, 0, stream>>>(deg, NN, (int*)x1k, NG * 512 + NG);
    k_hist<<<(NEP + 255) / 256, 256, 0, stream>>>(dst, deg);
    k_scan1<<<nb, SCAN_B, 0, stream>>>(deg, excl, partials, NN);
    k_scan2<<<1, SCAN_B, 0, stream>>>(partials, nb);
    k_scan3<<<nb, SCAN_B, 0, stream>>>(excl, partials, rowptr, cursor, NN);
    k_scatter<<<(NEP + 255) / 256, 256, 0, stream>>>(src, dst, cursor, srcsort);

    // -------- weight prep --------
    k_prep3<<<320, 256, 0, stream>>>(Wl[0], asl[0], adl[0], Wb0, wa0, wb0,
                                     Wl[1], asl[1], adl[1], Wb1, wa1, wb1,
                                     Wl[2], asl[2], adl[2], Wb2, wa2, wb2);

    // -------- layer 1 --------
    k_st128<<<AB, 256, 0, stream>>>(x_in, wa0, wb0, sA, tA);
    k_gemm_mfma<128, 64, true><<<GB, 256, 0, stream>>>(x_in, Wb0, Hb);
    k_agg_w<64><<<AB, 256, 0, stream>>>(rowptr, srcsort, sA, tA, Hb, bl[0], Xb, wa1, wb1, sB, tB);

    // -------- layer 2 --------
    k_gemm_mfma<64, 128, false><<<GB, 256, 0, stream>>>(Xb, Wb1, Hb);
    k_agg_w<128><<<AB, 256, 0, stream>>>(rowptr, srcsort, sB, tB, Hb, bl[1], Xb, wa2, wb2, sA, tA);

    // -------- layer 3 --------
    k_gemm_mfma<128, 256, false><<<GB, 256, 0, stream>>>(Xb, Wb2, Hb);
    k_agg256<<<AB, 256, 0, stream>>>(rowptr, srcsort, sA, tA, Hb, bl[2], Xb3);

    // -------- pooling + fused tail --------
    k_pool2<<<(NN + 63) / 64, 256, 0, stream>>>(Xb3, batch, x1k, x2, cnt);
    k_tail<<<NG, 256, 0, stream>>>(x1k, x2, cnt,
                                   d1w, d1b, d2w, d2b, d3w, d3b, mw, mb,
                                   d4w, d4b, d5w, d5b, d6w, d6b, d7w, d7b,
                                   (float*)d_out);
}